// Round 6
// baseline (861.578 us; speedup 1.0000x reference)
//
#include <hip/hip_runtime.h>
#include <hip/hip_cooperative_groups.h>
#include <stdint.h>

namespace cg = cooperative_groups;

static constexpr int T_STEPS = 15;
static constexpr int C_IN = 6;
static constexpr int C_OUT = 64;
static constexpr int H = 256;
static constexpr int W = 256;
static constexpr int NPOS = H * W;            // 65536
static constexpr int NTAP = 150;              // 6*5*5
#define DTHRESH 15.0

typedef float vfloat4 __attribute__((ext_vector_type(4)));

// workspace layout (bytes)
static constexpr size_t WS_FT     = 0;                              // uint8 [C_IN*NPOS]
static constexpr size_t WS_SERIES = 393216;                         // float [NPOS*16]
static constexpr size_t WS_WINC   = WS_SERIES + (size_t)NPOS*16*4;  // int8  [NPOS]
static constexpr size_t WS_NMAP   = WS_WINC + (size_t)NPOS;         // uint8 [NPOS]
static constexpr size_t WS_VAL    = WS_NMAP + (size_t)NPOS;         // double[NPOS]
static constexpr size_t WS_RED    = WS_VAL + (size_t)NPOS*8;        // double[128]: round partials par0/par1 (2x64)
static constexpr size_t WS_RIX    = WS_RED + 128*8;                 // uint32[128]: round indices par0/par1
static constexpr size_t WS_NEED   = WS_RIX + 128*4;

// ---------------- K1: first-spike-time map ----------------
__global__ __launch_bounds__(256) void ft_kernel(const float* __restrict__ x,
                                                 uint8_t* __restrict__ ft) {
    int i = blockIdx.x * 256 + threadIdx.x;
    if (i >= C_IN * NPOS) return;
    int f = 15;
    #pragma unroll
    for (int t = T_STEPS - 1; t >= 0; --t) {
        if (x[(size_t)t * (C_IN * NPOS) + i] > 0.0f) f = t;
    }
    ft[i] = (uint8_t)f;
}

// ---------------- K2: per-position conv-as-sorted-accumulate + pointwise WTA ----------------
// ONE position per wave (no iter loop). Block = 8 waves = 8 consecutive w.
// LDS: 38656 (w) + 360 (ft tile) + 512 (cnt) + 1632 (srt, +4B overread pad)
//    = 41160 B -> 3 blocks/CU = 24 waves/CU = 6 waves/SIMD (1.5x prior occupancy).
// Chunk loop software-pipelines the srt word: buckets are 4-aligned, so the word
// at A+q+4 is ALWAYS the next chunk's word (even across bucket boundaries and
// empty buckets) -> srt latency leaves the dependency chain.
__global__ __launch_bounds__(512, 6) void conv_kernel(
        const float* __restrict__ w1, const uint8_t* __restrict__ ftg,
        float* __restrict__ series_ws, int8_t* __restrict__ winc_ws,
        uint8_t* __restrict__ nmap_ws, double* __restrict__ val_ws)
{
    __shared__ float w_lds[(NTAP + 1) * 64];                 // [tap][o]; row 150 = zeros
    __shared__ uint8_t ft_lds[6 * 5 * 12];                   // [c][kh][col 0..11]
    __shared__ alignas(16) unsigned cnt_lds[8][16];          // per-wave
    __shared__ alignas(8) uint8_t sorted_lds[8][204];        // per-wave, 4-aligned buckets + pad

    int tid = threadIdx.x;
    int bid = blockIdx.x;                        // 0..8191
    int h  = bid >> 5;
    int w0 = (bid & 31) << 3;

    // stage weights transposed: w_lds[tap*64 + o] = w1[o*150 + tap] (coalesced reads)
    for (int i = tid; i < C_OUT * NTAP; i += 512) {
        int o = i / NTAP;
        int tap = i - o * NTAP;
        w_lds[tap * 64 + o] = w1[i];
    }
    if (tid < 64) w_lds[NTAP * 64 + tid] = 0.0f;             // zero row for pad slots
    // stage ft tile with pad-of-15 (never spikes) outside the image
    for (int i = tid; i < 360; i += 512) {
        int c = i / 60;
        int r = i - c * 60;
        int kh = r / 12;
        int j  = r - kh * 12;
        int gh = h - 2 + kh;
        int gw = w0 - 2 + j;
        uint8_t v = 15;
        if (gh >= 0 && gh < H && gw >= 0 && gw < W) v = ftg[c * NPOS + gh * W + gw];
        ft_lds[(c * 5 + kh) * 12 + j] = v;
    }
    __syncthreads();   // the ONLY block barrier

    int lane = tid & 63;
    int wvi  = tid >> 6;                         // 0..7 = my column
    unsigned* cnt = cnt_lds[wvi];
    uint8_t* srt = sorted_lds[wvi];

    int xl = wvi;                                // local col
    int p  = h * W + w0 + xl;

    if (lane < 16) cnt[lane] = 0;                // wave-private, no barrier

    // counting sort of the 150 taps by first-spike time (3 tap slots per lane)
    int tap0 = lane, tap1 = lane + 64, tap2 = lane + 128;
    auto ftv = [&](int tap) -> unsigned {
        int c = tap / 25;
        int r = tap - c * 25;
        int kh = r / 5;
        int kw = r - kh * 5;
        return ft_lds[(c * 5 + kh) * 12 + xl + kw];
    };
    unsigned f0 = ftv(tap0);
    unsigned f1 = ftv(tap1);
    unsigned f2 = (tap2 < NTAP) ? ftv(tap2) : 15u;
    unsigned r0 = 0, r1 = 0, r2 = 0;
    if (f0 < 15u) r0 = atomicAdd(&cnt[f0], 1u);
    if (f1 < 15u) r1 = atomicAdd(&cnt[f1], 1u);
    if (f2 < 15u) r2 = atomicAdd(&cnt[f2], 1u);

    // read all 16 counts via 4 vector loads (broadcast)
    uint4 c4[4];
    #pragma unroll
    for (int i = 0; i < 4; ++i) c4[i] = ((const uint4*)cnt)[i];
    unsigned cv_t[16];
    #pragma unroll
    for (int i = 0; i < 4; ++i) {
        cv_t[4*i+0] = c4[i].x; cv_t[4*i+1] = c4[i].y;
        cv_t[4*i+2] = c4[i].z; cv_t[4*i+3] = c4[i].w;
    }
    int kt[15];
    #pragma unroll
    for (int t = 0; t < 15; ++t) kt[t] = (int)__builtin_amdgcn_readfirstlane(cv_t[t]);

    // aligned-4 bucket starts: per-lane predicated prefix of align4(counts)
    unsigned st0 = 0, st1 = 0, st2 = 0, stp = 0;
    #pragma unroll
    for (int t = 0; t < 15; ++t) {
        unsigned a = (cv_t[t] + 3u) & ~3u;
        if ((unsigned)t < f0) st0 += a;
        if ((unsigned)t < f1) st1 += a;
        if ((unsigned)t < f2) st2 += a;
        if (t < lane) stp += a;                  // pad-fill prefix for lane==t bucket
    }
    if (f0 < 15u) srt[st0 + r0] = (uint8_t)tap0;
    if (f1 < 15u) srt[st1 + r1] = (uint8_t)tap1;
    if (f2 < 15u) srt[st2 + r2] = (uint8_t)tap2;

    // fill pad slots of bucket t=lane (lane<15) with tap 150 (zero weight)
    if (lane < 15) {
        unsigned kk = cnt[lane];                 // final count for this bucket
        unsigned a4 = (kk + 3u) & ~3u;
        if (kk     < a4) srt[stp + kk]     = (uint8_t)NTAP;
        if (kk + 1 < a4) srt[stp + kk + 1] = (uint8_t)NTAP;
        if (kk + 2 < a4) srt[stp + kk + 2] = (uint8_t)NTAP;
    }

    // main accumulate: software-pipelined srt word. pr holds chunk j's word while
    // chunk j+1's word loads (overread lands in the 4B pad). fp32 pairwise sum +
    // one cvt + one add_f64. All slots valid (pads hit the zero row).
    double run = 0.0, cvv = 0.0;
    int tc = 127;
    float ser[15];
    int A = 0;                                   // aligned bucket start
    unsigned pr = *(const unsigned*)(srt);       // first chunk word (valid even if k0==0)
    #pragma unroll
    for (int t = 0; t < 15; ++t) {
        int k = kt[t];
        for (int q = 0; q < k; q += 4) {
            unsigned nxt = *(const unsigned*)(srt + A + q + 4);  // next chunk (seamless)
            float wa  = w_lds[((pr       & 0xFFu) << 6) + lane];
            float wb  = w_lds[(((pr >> 8) & 0xFFu) << 6) + lane];
            float wcf = w_lds[(((pr >> 16) & 0xFFu) << 6) + lane];
            float wd  = w_lds[(( pr >> 24        ) << 6) + lane];
            float s   = (wa + wb) + (wcf + wd);                  // fp32 pairwise
            run += (double)s;                                    // one cvt + one add_f64
            pr = nxt;
        }
        A += (k + 3) & ~3;
        ser[t] = (float)run;
        bool cross_now = (tc == 127) && (run >= DTHRESH);
        if (cross_now) { tc = t; cvv = run; }                // cndmask, no branch
    }

    // cross-lane: e = min crossing time; winner = max cvv among tc==e, first-lane tie
    int e = tc;
    #pragma unroll
    for (int off = 32; off >= 1; off >>= 1) e = min(e, __shfl_xor(e, off));
    int wc = -1;
    double val = 0.0;
    if (e < 15) {                                // uniform branch
        double vl = (tc == e) ? cvv : 0.0;
        double m = vl;
        #pragma unroll
        for (int off = 32; off >= 1; off >>= 1) m = fmax(m, __shfl_xor(m, off));
        unsigned long long mk = __ballot(vl == m);
        wc = __ffsll(mk) - 1;
        val = m;

        // winner's series -> lanes 0..14 via shfl, zero before crossing
        float ov = 0.0f;
        #pragma unroll
        for (int t = 0; t < 15; ++t) {
            float sv = __shfl(ser[t], wc);
            if (lane == t) ov = sv;
        }
        if (lane < e) ov = 0.0f;                 // monotone: below thresh before e
        if (lane < 15) series_ws[p * 16 + lane] = ov;
    }
    if (lane == 0) {
        winc_ws[p] = (int8_t)wc;
        nmap_ws[p] = (uint8_t)(wc >= 0 ? (15 - e) : 0);
        if (wc >= 0) val_ws[p] = val;
    }
}

// ---------------- K3: cooperative 5-round k-winners (lexicographic key, 64 blocks) ----------------
// R3 version verbatim (known-good). Key = nm*2048 + val orders exactly as the
// reference's nm*(val + 15*max_val); 5 grid syncs total.
__global__ __launch_bounds__(256) void kwin_kernel(
        const int8_t* __restrict__ winc, const uint8_t* __restrict__ nmap,
        const double* __restrict__ val, float* __restrict__ outw,
        double* __restrict__ redv, unsigned* __restrict__ redi)
{
    cg::grid_group grid = cg::this_grid();
    const int tid  = threadIdx.x;
    const int bid  = blockIdx.x;
    const int lane = tid & 63, wvi = tid >> 6;

    __shared__ double   s_v[4];
    __shared__ unsigned s_i[4];

    int     pc[4];
    int     phh[4], pww[4];
    double  key[4];
    unsigned idx[4];
    bool    alive[4];
    #pragma unroll
    for (int k = 0; k < 4; ++k) {
        const int p = (k << 14) | (bid << 8) | tid;      // coalesced per k
        const int c = winc[p];
        alive[k] = (c >= 0);
        const double vp = alive[k] ? val[p] : 0.0;       // val only valid where winner exists
        key[k]  = (double)nmap[p] * 2048.0 + vp;         // lex (nm, val) in one double
        idx[k]  = ((unsigned)c << 16) | (unsigned)p;     // c-major flat index (tie-break)
        pc[k]   = c;
        phh[k]  = p >> 8;
        pww[k]  = p & 255;
    }

    for (int r = 0; r < 5; ++r) {
        __syncthreads();                          // protect s_v/s_i reuse across rounds
        const int par = r & 1;

        // best among my 4 positions (static indexing -> registers)
        double   bv = -1.0;
        unsigned bi = 0xFFFFFFFFu;
        #pragma unroll
        for (int k = 0; k < 4; ++k) {
            if (alive[k] && (key[k] > bv || (key[k] == bv && idx[k] < bi))) {
                bv = key[k]; bi = idx[k];
            }
        }
        // wave argmax with (key desc, fi asc) ordering
        #pragma unroll
        for (int off = 32; off >= 1; off >>= 1) {
            double   ov = __shfl_xor(bv, off);
            unsigned oi = __shfl_xor(bi, off);
            if (ov > bv || (ov == bv && oi < bi)) { bv = ov; bi = oi; }
        }
        if (lane == 0) { s_v[wvi] = bv; s_i[wvi] = bi; }
        __syncthreads();
        if (tid == 0) {
            double bbv = s_v[0]; unsigned bbi = s_i[0];
            #pragma unroll
            for (int i = 1; i < 4; ++i)
                if (s_v[i] > bbv || (s_v[i] == bbv && s_i[i] < bbi)) { bbv = s_v[i]; bbi = s_i[i]; }
            redv[par * 64 + bid] = bbv;
            redi[par * 64 + bid] = bbi;
        }
        grid.sync();

        // wave 0 of every block reduces the 64 partials -> identical winner everywhere
        if (wvi == 0) {
            double   gv = redv[par * 64 + lane];
            unsigned gi = redi[par * 64 + lane];
            #pragma unroll
            for (int off = 32; off >= 1; off >>= 1) {
                double   ov = __shfl_xor(gv, off);
                unsigned oi = __shfl_xor(gi, off);
                if (ov > gv || (ov == gv && oi < gi)) { gv = ov; gi = oi; }
            }
            if (lane == 0) { s_v[0] = gv; s_i[0] = gi; }
        }
        __syncthreads();
        const double   bbv = s_v[0];
        const unsigned bbi = s_i[0];

        const bool valid = (bbv > 0.0);          // any alive position has key >= 2048+15
        if (bid == 0 && tid == 0) {
            int wc2 = (int)(bbi >> 16), pp = (int)(bbi & 0xFFFFu);
            outw[r * 3 + 0] = valid ? (float)wc2       : -1.0f;
            outw[r * 3 + 1] = valid ? (float)(pp >> 8) : -1.0f;
            outw[r * 3 + 2] = valid ? (float)(pp & 255): -1.0f;
        }
        if (valid) {
            const int wc2 = (int)(bbi >> 16);
            const int wp  = (int)(bbi & 0xFFFFu);
            const int wh  = wp >> 8, wwv = wp & 255;
            #pragma unroll
            for (int k = 0; k < 4; ++k) {
                if (pc[k] == wc2 || (phh[k] >= wh - 3 && phh[k] <= wh + 3 &&
                                     pww[k] >= wwv - 3 && pww[k] <= wwv + 3)) alive[k] = false;
            }
        }
        // invalid round => all totals zero => later rounds invalid too (reference's
        // phantom kill of an all-zero total is inert for outputs)
    }
}

// ---------------- K4: sparse scatter of winner series (zeros come from memset) ----------------
// One thread per position. Non-winners: early-out (memset already wrote 0).
// Winners: 15 x 2 scalar stores (pot value + spk indicator) into the winner
// channel's planes. ~8 MB effective traffic vs 503 MB of kernel zero-writes.
__global__ __launch_bounds__(256) void scatter_kernel(
        const int8_t* __restrict__ winc, const float* __restrict__ series,
        float* __restrict__ spk, float* __restrict__ pot)
{
    int p = blockIdx.x * 256 + threadIdx.x;      // 0..65535
    int c = winc[p];
    if (c < 0) return;
    const vfloat4* sp = reinterpret_cast<const vfloat4*>(series + (size_t)p * 16);
    vfloat4 q0 = sp[0], q1 = sp[1], q2 = sp[2], q3 = sp[3];
    float sv[16];
    #pragma unroll
    for (int j = 0; j < 4; ++j) { sv[j] = q0[j]; sv[4+j] = q1[j]; sv[8+j] = q2[j]; sv[12+j] = q3[j]; }
    size_t base = (size_t)c * NPOS + (size_t)p;
    #pragma unroll
    for (int t = 0; t < 15; ++t) {
        float xv = sv[t];
        pot[(size_t)t * (C_OUT * NPOS) + base] = xv;
        spk[(size_t)t * (C_OUT * NPOS) + base] = (xv > 0.f) ? 1.0f : 0.0f;
    }
}

extern "C" void kernel_launch(void* const* d_in, const int* in_sizes, int n_in,
                              void* d_out, int out_size, void* d_ws, size_t ws_size,
                              hipStream_t stream)
{
    if (ws_size < WS_NEED) return;

    const float* x  = (const float*)d_in[0];
    const float* w1 = (const float*)d_in[1];
    uint8_t* ws = (uint8_t*)d_ws;
    uint8_t* ftg    = ws + WS_FT;
    float*   series = (float*)(ws + WS_SERIES);
    int8_t*  winc   = (int8_t*)(ws + WS_WINC);
    uint8_t* nmap   = (uint8_t*)(ws + WS_NMAP);
    double*  val    = (double*)(ws + WS_VAL);
    double*  redv   = (double*)(ws + WS_RED);
    unsigned* redi  = (unsigned*)(ws + WS_RIX);

    float* spk  = (float*)d_out;
    float* pot  = spk + (size_t)T_STEPS * C_OUT * NPOS;
    float* outw = pot + (size_t)T_STEPS * C_OUT * NPOS;

    // zero spk+pot at fill-rate (graph-capturable memset node); scatter fills winners
    hipMemsetAsync(d_out, 0, (size_t)2 * T_STEPS * C_OUT * NPOS * sizeof(float), stream);

    hipLaunchKernelGGL(ft_kernel,     dim3(1536),  dim3(256),  0, stream, x, ftg);
    hipLaunchKernelGGL(conv_kernel,   dim3(8192),  dim3(512),  0, stream, w1, ftg, series, winc, nmap, val);

    void* kargs[] = { (void*)&winc, (void*)&nmap, (void*)&val,
                      (void*)&outw, (void*)&redv, (void*)&redi };
    hipLaunchCooperativeKernel((const void*)kwin_kernel, dim3(64), dim3(256), kargs, 0, stream);

    hipLaunchKernelGGL(scatter_kernel, dim3(256),  dim3(256),  0, stream, winc, series, spk, pot);
}

// Round 7
// 824.725 us; speedup vs baseline: 1.0447x; 1.0447x over previous
//
#include <hip/hip_runtime.h>
#include <hip/hip_cooperative_groups.h>
#include <stdint.h>

namespace cg = cooperative_groups;

static constexpr int T_STEPS = 15;
static constexpr int C_IN = 6;
static constexpr int C_OUT = 64;
static constexpr int H = 256;
static constexpr int W = 256;
static constexpr int NPOS = H * W;            // 65536
static constexpr int NTAP = 150;              // 6*5*5
#define DTHRESH 15.0

typedef float vfloat4 __attribute__((ext_vector_type(4)));

// workspace layout (bytes)
static constexpr size_t WS_FT     = 0;                              // uint8 [C_IN*NPOS]
static constexpr size_t WS_SERIES = 393216;                         // float [NPOS*16]
static constexpr size_t WS_WINC   = WS_SERIES + (size_t)NPOS*16*4;  // int8  [NPOS]
static constexpr size_t WS_NMAP   = WS_WINC + (size_t)NPOS;         // uint8 [NPOS]
static constexpr size_t WS_VAL    = WS_NMAP + (size_t)NPOS;         // double[NPOS]
static constexpr size_t WS_RED    = WS_VAL + (size_t)NPOS*8;        // double[128]: round partials par0/par1 (2x64)
static constexpr size_t WS_RIX    = WS_RED + 128*8;                 // uint32[128]: round indices par0/par1
static constexpr size_t WS_NEED   = WS_RIX + 128*4;

// ---------------- K1: first-spike-time map ----------------
__global__ __launch_bounds__(256) void ft_kernel(const float* __restrict__ x,
                                                 uint8_t* __restrict__ ft) {
    int i = blockIdx.x * 256 + threadIdx.x;
    if (i >= C_IN * NPOS) return;
    int f = 15;
    #pragma unroll
    for (int t = T_STEPS - 1; t >= 0; --t) {
        if (x[(size_t)t * (C_IN * NPOS) + i] > 0.0f) f = t;
    }
    ft[i] = (uint8_t)f;
}

// ---------------- K2: per-position conv-as-sorted-accumulate + pointwise WTA ----------------
// R5 version VERBATIM (known-good, ~248 us). One wave per (h,w); lane = output
// channel. Block = 4 waves, 16 consecutive w. Zero-weight tap row + pad fill ->
// branch-free accumulate; fp32 pairwise chunk sum + one fp64 accumulate.
// LDS: 38656 + 600 + 256 + 800 = 40312 B -> 4 blocks/CU.
__global__ __launch_bounds__(256, 4) void conv_kernel(
        const float* __restrict__ w1, const uint8_t* __restrict__ ftg,
        float* __restrict__ series_ws, int8_t* __restrict__ winc_ws,
        uint8_t* __restrict__ nmap_ws, double* __restrict__ val_ws)
{
    __shared__ float w_lds[(NTAP + 1) * 64];                 // [tap][o]; row 150 = zeros
    __shared__ uint8_t ft_lds[6 * 5 * 20];                   // [c][kh][col 0..19]
    __shared__ alignas(16) unsigned cnt_lds[4][16];          // per-wave
    __shared__ alignas(8) uint8_t sorted_lds[4][200];        // per-wave, 4-aligned buckets, u8 tap ids

    int tid = threadIdx.x;
    int bid = blockIdx.x;                        // 0..4095
    int h  = bid >> 4;
    int w0 = (bid & 15) << 4;

    // stage weights transposed: w_lds[tap*64 + o] = w1[o*150 + tap] (coalesced reads)
    for (int i = tid; i < C_OUT * NTAP; i += 256) {
        int o = i / NTAP;
        int tap = i - o * NTAP;
        w_lds[tap * 64 + o] = w1[i];
    }
    if (tid < 64) w_lds[NTAP * 64 + tid] = 0.0f;             // zero row for pad slots
    // stage ft tile with pad-of-15 (never spikes) outside the image
    for (int i = tid; i < 600; i += 256) {
        int c = i / 100;
        int r = i - c * 100;
        int kh = r / 20;
        int j  = r - kh * 20;
        int gh = h - 2 + kh;
        int gw = w0 - 2 + j;
        uint8_t v = 15;
        if (gh >= 0 && gh < H && gw >= 0 && gw < W) v = ftg[c * NPOS + gh * W + gw];
        ft_lds[(c * 5 + kh) * 20 + j] = v;
    }
    __syncthreads();   // the ONLY block barrier

    int lane = tid & 63;
    int wvi  = tid >> 6;
    unsigned* cnt = cnt_lds[wvi];
    uint8_t* srt = sorted_lds[wvi];

    for (int iter = 0; iter < 4; ++iter) {
        int xl = iter * 4 + wvi;                 // local col 0..15
        int p  = h * W + w0 + xl;

        if (lane < 16) cnt[lane] = 0;            // wave-private, no barrier

        // counting sort of the 150 taps by first-spike time (3 tap slots per lane)
        int tap0 = lane, tap1 = lane + 64, tap2 = lane + 128;
        auto ftv = [&](int tap) -> unsigned {
            int c = tap / 25;
            int r = tap - c * 25;
            int kh = r / 5;
            int kw = r - kh * 5;
            return ft_lds[(c * 5 + kh) * 20 + xl + kw];
        };
        unsigned f0 = ftv(tap0);
        unsigned f1 = ftv(tap1);
        unsigned f2 = (tap2 < NTAP) ? ftv(tap2) : 15u;
        unsigned r0 = 0, r1 = 0, r2 = 0;
        if (f0 < 15u) r0 = atomicAdd(&cnt[f0], 1u);
        if (f1 < 15u) r1 = atomicAdd(&cnt[f1], 1u);
        if (f2 < 15u) r2 = atomicAdd(&cnt[f2], 1u);

        // read all 16 counts via 4 vector loads (broadcast)
        uint4 c4[4];
        #pragma unroll
        for (int i = 0; i < 4; ++i) c4[i] = ((const uint4*)cnt)[i];
        unsigned cv_t[16];
        #pragma unroll
        for (int i = 0; i < 4; ++i) {
            cv_t[4*i+0] = c4[i].x; cv_t[4*i+1] = c4[i].y;
            cv_t[4*i+2] = c4[i].z; cv_t[4*i+3] = c4[i].w;
        }
        int kt[15];
        #pragma unroll
        for (int t = 0; t < 15; ++t) kt[t] = (int)__builtin_amdgcn_readfirstlane(cv_t[t]);

        // aligned-4 bucket starts: per-lane predicated prefix of align4(counts)
        unsigned st0 = 0, st1 = 0, st2 = 0, stp = 0;
        #pragma unroll
        for (int t = 0; t < 15; ++t) {
            unsigned a = (cv_t[t] + 3u) & ~3u;
            if ((unsigned)t < f0) st0 += a;
            if ((unsigned)t < f1) st1 += a;
            if ((unsigned)t < f2) st2 += a;
            if (t < lane) stp += a;              // pad-fill prefix for lane==t bucket
        }
        if (f0 < 15u) srt[st0 + r0] = (uint8_t)tap0;
        if (f1 < 15u) srt[st1 + r1] = (uint8_t)tap1;
        if (f2 < 15u) srt[st2 + r2] = (uint8_t)tap2;

        // fill pad slots of bucket t=lane (lane<15) with tap 150 (zero weight)
        if (lane < 15) {
            unsigned kk = cnt[lane];             // final count for this bucket
            unsigned a4 = (kk + 3u) & ~3u;
            if (kk     < a4) srt[stp + kk]     = (uint8_t)NTAP;
            if (kk + 1 < a4) srt[stp + kk + 1] = (uint8_t)NTAP;
            if (kk + 2 < a4) srt[stp + kk + 2] = (uint8_t)NTAP;
        }

        // main accumulate: per chunk-of-4: one b32 srt read + 4 b32 w reads +
        // fp32 pairwise sum + single fp64 accumulate. All slots valid (pads hit
        // the zero row) -> no clamps, no predication.
        double run = 0.0, cvv = 0.0;
        int tc = 127;
        float ser[15];
        int A = 0;                               // aligned bucket start
        #pragma unroll
        for (int t = 0; t < 15; ++t) {
            int k = kt[t];
            for (int q = 0; q < k; q += 4) {
                unsigned pr = *(const unsigned*)(srt + A + q);   // 4 sorted tap ids, broadcast
                float wa  = w_lds[((pr       & 0xFFu) << 6) + lane];
                float wb  = w_lds[(((pr >> 8) & 0xFFu) << 6) + lane];
                float wcf = w_lds[(((pr >> 16) & 0xFFu) << 6) + lane];
                float wd  = w_lds[(( pr >> 24        ) << 6) + lane];
                float s   = (wa + wb) + (wcf + wd);              // fp32 pairwise
                run += (double)s;                                // one cvt + one add_f64
            }
            A += (k + 3) & ~3;
            ser[t] = (float)run;
            bool cross_now = (tc == 127) && (run >= DTHRESH);
            if (cross_now) { tc = t; cvv = run; }            // cndmask, no branch
        }

        // cross-lane: e = min crossing time; winner = max cvv among tc==e, first-lane tie
        int e = tc;
        #pragma unroll
        for (int off = 32; off >= 1; off >>= 1) e = min(e, __shfl_xor(e, off));
        int wc = -1;
        double val = 0.0;
        if (e < 15) {                                    // uniform branch
            double vl = (tc == e) ? cvv : 0.0;
            double m = vl;
            #pragma unroll
            for (int off = 32; off >= 1; off >>= 1) m = fmax(m, __shfl_xor(m, off));
            unsigned long long mk = __ballot(vl == m);
            wc = __ffsll(mk) - 1;
            val = m;

            // winner's series -> lanes 0..14 via shfl, zero before crossing
            float ov = 0.0f;
            #pragma unroll
            for (int t = 0; t < 15; ++t) {
                float sv = __shfl(ser[t], wc);
                if (lane == t) ov = sv;
            }
            if (lane < e) ov = 0.0f;                     // monotone: below thresh before e
            if (lane < 15) series_ws[p * 16 + lane] = ov;
        }
        if (lane == 0) {
            winc_ws[p] = (int8_t)wc;
            nmap_ws[p] = (uint8_t)(wc >= 0 ? (15 - e) : 0);
            if (wc >= 0) val_ws[p] = val;
        }
    }
}

// ---------------- K3: cooperative 5-round k-winners (lexicographic key, 64 blocks) ----------------
// R3 version verbatim (known-good). Key = nm*2048 + val orders exactly as the
// reference's nm*(val + 15*max_val); 5 grid syncs total.
__global__ __launch_bounds__(256) void kwin_kernel(
        const int8_t* __restrict__ winc, const uint8_t* __restrict__ nmap,
        const double* __restrict__ val, float* __restrict__ outw,
        double* __restrict__ redv, unsigned* __restrict__ redi)
{
    cg::grid_group grid = cg::this_grid();
    const int tid  = threadIdx.x;
    const int bid  = blockIdx.x;
    const int lane = tid & 63, wvi = tid >> 6;

    __shared__ double   s_v[4];
    __shared__ unsigned s_i[4];

    int     pc[4];
    int     phh[4], pww[4];
    double  key[4];
    unsigned idx[4];
    bool    alive[4];
    #pragma unroll
    for (int k = 0; k < 4; ++k) {
        const int p = (k << 14) | (bid << 8) | tid;      // coalesced per k
        const int c = winc[p];
        alive[k] = (c >= 0);
        const double vp = alive[k] ? val[p] : 0.0;       // val only valid where winner exists
        key[k]  = (double)nmap[p] * 2048.0 + vp;         // lex (nm, val) in one double
        idx[k]  = ((unsigned)c << 16) | (unsigned)p;     // c-major flat index (tie-break)
        pc[k]   = c;
        phh[k]  = p >> 8;
        pww[k]  = p & 255;
    }

    for (int r = 0; r < 5; ++r) {
        __syncthreads();                          // protect s_v/s_i reuse across rounds
        const int par = r & 1;

        // best among my 4 positions (static indexing -> registers)
        double   bv = -1.0;
        unsigned bi = 0xFFFFFFFFu;
        #pragma unroll
        for (int k = 0; k < 4; ++k) {
            if (alive[k] && (key[k] > bv || (key[k] == bv && idx[k] < bi))) {
                bv = key[k]; bi = idx[k];
            }
        }
        // wave argmax with (key desc, fi asc) ordering
        #pragma unroll
        for (int off = 32; off >= 1; off >>= 1) {
            double   ov = __shfl_xor(bv, off);
            unsigned oi = __shfl_xor(bi, off);
            if (ov > bv || (ov == bv && oi < bi)) { bv = ov; bi = oi; }
        }
        if (lane == 0) { s_v[wvi] = bv; s_i[wvi] = bi; }
        __syncthreads();
        if (tid == 0) {
            double bbv = s_v[0]; unsigned bbi = s_i[0];
            #pragma unroll
            for (int i = 1; i < 4; ++i)
                if (s_v[i] > bbv || (s_v[i] == bbv && s_i[i] < bbi)) { bbv = s_v[i]; bbi = s_i[i]; }
            redv[par * 64 + bid] = bbv;
            redi[par * 64 + bid] = bbi;
        }
        grid.sync();

        // wave 0 of every block reduces the 64 partials -> identical winner everywhere
        if (wvi == 0) {
            double   gv = redv[par * 64 + lane];
            unsigned gi = redi[par * 64 + lane];
            #pragma unroll
            for (int off = 32; off >= 1; off >>= 1) {
                double   ov = __shfl_xor(gv, off);
                unsigned oi = __shfl_xor(gi, off);
                if (ov > gv || (ov == gv && oi < gi)) { gv = ov; gi = oi; }
            }
            if (lane == 0) { s_v[0] = gv; s_i[0] = gi; }
        }
        __syncthreads();
        const double   bbv = s_v[0];
        const unsigned bbi = s_i[0];

        const bool valid = (bbv > 0.0);          // any alive position has key >= 2048+15
        if (bid == 0 && tid == 0) {
            int wc2 = (int)(bbi >> 16), pp = (int)(bbi & 0xFFFFu);
            outw[r * 3 + 0] = valid ? (float)wc2       : -1.0f;
            outw[r * 3 + 1] = valid ? (float)(pp >> 8) : -1.0f;
            outw[r * 3 + 2] = valid ? (float)(pp & 255): -1.0f;
        }
        if (valid) {
            const int wc2 = (int)(bbi >> 16);
            const int wp  = (int)(bbi & 0xFFFFu);
            const int wh  = wp >> 8, wwv = wp & 255;
            #pragma unroll
            for (int k = 0; k < 4; ++k) {
                if (pc[k] == wc2 || (phh[k] >= wh - 3 && phh[k] <= wh + 3 &&
                                     pww[k] >= wwv - 3 && pww[k] <= wwv + 3)) alive[k] = false;
            }
        }
        // invalid round => all totals zero => later rounds invalid too (reference's
        // phantom kill of an all-zero total is inert for outputs)
    }
}

// ---------------- K4: sparse scatter of winner series (zeros come from memset) ----------------
// One thread per position. Non-winners: early-out (memset already wrote 0).
// Winners: 15 x 2 scalar stores (pot value + spk indicator) into the winner
// channel's planes. ~8 MB effective traffic vs 503 MB of kernel zero-writes.
__global__ __launch_bounds__(256) void scatter_kernel(
        const int8_t* __restrict__ winc, const float* __restrict__ series,
        float* __restrict__ spk, float* __restrict__ pot)
{
    int p = blockIdx.x * 256 + threadIdx.x;      // 0..65535
    int c = winc[p];
    if (c < 0) return;
    const vfloat4* sp = reinterpret_cast<const vfloat4*>(series + (size_t)p * 16);
    vfloat4 q0 = sp[0], q1 = sp[1], q2 = sp[2], q3 = sp[3];
    float sv[16];
    #pragma unroll
    for (int j = 0; j < 4; ++j) { sv[j] = q0[j]; sv[4+j] = q1[j]; sv[8+j] = q2[j]; sv[12+j] = q3[j]; }
    size_t base = (size_t)c * NPOS + (size_t)p;
    #pragma unroll
    for (int t = 0; t < 15; ++t) {
        float xv = sv[t];
        pot[(size_t)t * (C_OUT * NPOS) + base] = xv;
        spk[(size_t)t * (C_OUT * NPOS) + base] = (xv > 0.f) ? 1.0f : 0.0f;
    }
}

extern "C" void kernel_launch(void* const* d_in, const int* in_sizes, int n_in,
                              void* d_out, int out_size, void* d_ws, size_t ws_size,
                              hipStream_t stream)
{
    if (ws_size < WS_NEED) return;

    const float* x  = (const float*)d_in[0];
    const float* w1 = (const float*)d_in[1];
    uint8_t* ws = (uint8_t*)d_ws;
    uint8_t* ftg    = ws + WS_FT;
    float*   series = (float*)(ws + WS_SERIES);
    int8_t*  winc   = (int8_t*)(ws + WS_WINC);
    uint8_t* nmap   = (uint8_t*)(ws + WS_NMAP);
    double*  val    = (double*)(ws + WS_VAL);
    double*  redv   = (double*)(ws + WS_RED);
    unsigned* redi  = (unsigned*)(ws + WS_RIX);

    float* spk  = (float*)d_out;
    float* pot  = spk + (size_t)T_STEPS * C_OUT * NPOS;
    float* outw = pot + (size_t)T_STEPS * C_OUT * NPOS;

    // zero spk+pot at fill-rate (graph-capturable memset node); scatter fills winners
    hipMemsetAsync(d_out, 0, (size_t)2 * T_STEPS * C_OUT * NPOS * sizeof(float), stream);

    hipLaunchKernelGGL(ft_kernel,     dim3(1536),  dim3(256),  0, stream, x, ftg);
    hipLaunchKernelGGL(conv_kernel,   dim3(4096),  dim3(256),  0, stream, w1, ftg, series, winc, nmap, val);

    void* kargs[] = { (void*)&winc, (void*)&nmap, (void*)&val,
                      (void*)&outw, (void*)&redv, (void*)&redi };
    hipLaunchCooperativeKernel((const void*)kwin_kernel, dim3(64), dim3(256), kargs, 0, stream);

    hipLaunchKernelGGL(scatter_kernel, dim3(256),  dim3(256),  0, stream, winc, series, spk, pot);
}

// Round 8
// 755.366 us; speedup vs baseline: 1.1406x; 1.0918x over previous
//
#include <hip/hip_runtime.h>
#include <hip/hip_cooperative_groups.h>
#include <stdint.h>

namespace cg = cooperative_groups;

static constexpr int T_STEPS = 15;
static constexpr int C_IN = 6;
static constexpr int C_OUT = 64;
static constexpr int H = 256;
static constexpr int W = 256;
static constexpr int NPOS = H * W;            // 65536
static constexpr int NTAP = 150;              // 6*5*5
#define DTHRESH 15.0

typedef float vfloat4 __attribute__((ext_vector_type(4)));

// workspace layout (bytes)
static constexpr size_t WS_FT     = 0;                              // uint8 [C_IN*NPOS]
static constexpr size_t WS_SERIES = 393216;                         // float [NPOS*16]
static constexpr size_t WS_WINC   = WS_SERIES + (size_t)NPOS*16*4;  // int8  [NPOS]
static constexpr size_t WS_NMAP   = WS_WINC + (size_t)NPOS;         // uint8 [NPOS]
static constexpr size_t WS_VAL    = WS_NMAP + (size_t)NPOS;         // double[NPOS]
static constexpr size_t WS_RED    = WS_VAL + (size_t)NPOS*8;        // double[128]: round partials par0/par1 (2x64)
static constexpr size_t WS_RIX    = WS_RED + 128*8;                 // uint32[128]: round indices par0/par1
static constexpr size_t WS_NEED   = WS_RIX + 128*4;

// ---------------- K1: first-spike-time map ----------------
__global__ __launch_bounds__(256) void ft_kernel(const float* __restrict__ x,
                                                 uint8_t* __restrict__ ft) {
    int i = blockIdx.x * 256 + threadIdx.x;
    if (i >= C_IN * NPOS) return;
    int f = 15;
    #pragma unroll
    for (int t = T_STEPS - 1; t >= 0; --t) {
        if (x[(size_t)t * (C_IN * NPOS) + i] > 0.0f) f = t;
    }
    ft[i] = (uint8_t)f;
}

// ---------------- K2: per-position conv-as-sorted-accumulate + pointwise WTA ----------------
// R5 structure; inner loop now processes TWO chunks (8 taps) per iteration to
// overlap LDS latency (addresses are loop-counter-derived, independent of run).
// Lane 15 writes one terminal pad word at stp==total so every readable word in
// [0, total+4) holds valid tap ids <= 150 -> no clamps. Second chunk's fp32 sum
// is predicated to 0.0f when q+4 >= k (run += 0.0 is exact), preserving R5's
// fp64 accumulation order bit-for-bit.
// LDS: 38656 + 600 + 256 + 800 = 40312 B -> 4 blocks/CU.
__global__ __launch_bounds__(256, 4) void conv_kernel(
        const float* __restrict__ w1, const uint8_t* __restrict__ ftg,
        float* __restrict__ series_ws, int8_t* __restrict__ winc_ws,
        uint8_t* __restrict__ nmap_ws, double* __restrict__ val_ws)
{
    __shared__ float w_lds[(NTAP + 1) * 64];                 // [tap][o]; row 150 = zeros
    __shared__ uint8_t ft_lds[6 * 5 * 20];                   // [c][kh][col 0..19]
    __shared__ alignas(16) unsigned cnt_lds[4][16];          // per-wave
    __shared__ alignas(8) uint8_t sorted_lds[4][200];        // per-wave, 4-aligned buckets, u8 tap ids

    int tid = threadIdx.x;
    int bid = blockIdx.x;                        // 0..4095
    int h  = bid >> 4;
    int w0 = (bid & 15) << 4;

    // stage weights transposed: w_lds[tap*64 + o] = w1[o*150 + tap] (coalesced reads)
    for (int i = tid; i < C_OUT * NTAP; i += 256) {
        int o = i / NTAP;
        int tap = i - o * NTAP;
        w_lds[tap * 64 + o] = w1[i];
    }
    if (tid < 64) w_lds[NTAP * 64 + tid] = 0.0f;             // zero row for pad slots
    // stage ft tile with pad-of-15 (never spikes) outside the image
    for (int i = tid; i < 600; i += 256) {
        int c = i / 100;
        int r = i - c * 100;
        int kh = r / 20;
        int j  = r - kh * 20;
        int gh = h - 2 + kh;
        int gw = w0 - 2 + j;
        uint8_t v = 15;
        if (gh >= 0 && gh < H && gw >= 0 && gw < W) v = ftg[c * NPOS + gh * W + gw];
        ft_lds[(c * 5 + kh) * 20 + j] = v;
    }
    __syncthreads();   // the ONLY block barrier

    int lane = tid & 63;
    int wvi  = tid >> 6;
    unsigned* cnt = cnt_lds[wvi];
    uint8_t* srt = sorted_lds[wvi];

    for (int iter = 0; iter < 4; ++iter) {
        int xl = iter * 4 + wvi;                 // local col 0..15
        int p  = h * W + w0 + xl;

        if (lane < 16) cnt[lane] = 0;            // wave-private, no barrier

        // counting sort of the 150 taps by first-spike time (3 tap slots per lane)
        int tap0 = lane, tap1 = lane + 64, tap2 = lane + 128;
        auto ftv = [&](int tap) -> unsigned {
            int c = tap / 25;
            int r = tap - c * 25;
            int kh = r / 5;
            int kw = r - kh * 5;
            return ft_lds[(c * 5 + kh) * 20 + xl + kw];
        };
        unsigned f0 = ftv(tap0);
        unsigned f1 = ftv(tap1);
        unsigned f2 = (tap2 < NTAP) ? ftv(tap2) : 15u;
        unsigned r0 = 0, r1 = 0, r2 = 0;
        if (f0 < 15u) r0 = atomicAdd(&cnt[f0], 1u);
        if (f1 < 15u) r1 = atomicAdd(&cnt[f1], 1u);
        if (f2 < 15u) r2 = atomicAdd(&cnt[f2], 1u);

        // read all 16 counts via 4 vector loads (broadcast)
        uint4 c4[4];
        #pragma unroll
        for (int i = 0; i < 4; ++i) c4[i] = ((const uint4*)cnt)[i];
        unsigned cv_t[16];
        #pragma unroll
        for (int i = 0; i < 4; ++i) {
            cv_t[4*i+0] = c4[i].x; cv_t[4*i+1] = c4[i].y;
            cv_t[4*i+2] = c4[i].z; cv_t[4*i+3] = c4[i].w;
        }
        int kt[15];
        #pragma unroll
        for (int t = 0; t < 15; ++t) kt[t] = (int)__builtin_amdgcn_readfirstlane(cv_t[t]);

        // aligned-4 bucket starts: per-lane predicated prefix of align4(counts)
        unsigned st0 = 0, st1 = 0, st2 = 0, stp = 0;
        #pragma unroll
        for (int t = 0; t < 15; ++t) {
            unsigned a = (cv_t[t] + 3u) & ~3u;
            if ((unsigned)t < f0) st0 += a;
            if ((unsigned)t < f1) st1 += a;
            if ((unsigned)t < f2) st2 += a;
            if (t < lane) stp += a;              // pad-fill prefix for lane==t bucket; lane 15: total
        }
        if (f0 < 15u) srt[st0 + r0] = (uint8_t)tap0;
        if (f1 < 15u) srt[st1 + r1] = (uint8_t)tap1;
        if (f2 < 15u) srt[st2 + r2] = (uint8_t)tap2;

        // fill pad slots of bucket t=lane (lane<15) with tap 150 (zero weight)
        if (lane < 15) {
            unsigned kk = cnt[lane];             // final count for this bucket
            unsigned a4 = (kk + 3u) & ~3u;
            if (kk     < a4) srt[stp + kk]     = (uint8_t)NTAP;
            if (kk + 1 < a4) srt[stp + kk + 1] = (uint8_t)NTAP;
            if (kk + 2 < a4) srt[stp + kk + 2] = (uint8_t)NTAP;
        }
        // lane 15: terminal pad word at stp == total aligned size, so the
        // paired-chunk overread at A+q+4 always lands on valid tap ids
        if (lane == 15) {
            srt[stp]     = (uint8_t)NTAP;
            srt[stp + 1] = (uint8_t)NTAP;
            srt[stp + 2] = (uint8_t)NTAP;
            srt[stp + 3] = (uint8_t)NTAP;
        }

        // main accumulate: TWO chunks per iteration (8 taps). Both srt words and
        // all 8 w reads are address-independent -> issue together, latency overlaps.
        // fp64 order identical to R5: run += s1; run += s2(or exact 0.0).
        double run = 0.0, cvv = 0.0;
        int tc = 127;
        float ser[15];
        int A = 0;                               // aligned bucket start
        #pragma unroll
        for (int t = 0; t < 15; ++t) {
            int k = kt[t];
            for (int q = 0; q < k; q += 8) {
                unsigned pr1 = *(const unsigned*)(srt + A + q);      // chunk 1 (always valid)
                unsigned pr2 = *(const unsigned*)(srt + A + q + 4);  // chunk 2 or next-bucket/terminal pad
                float wa1 = w_lds[((pr1       & 0xFFu) << 6) + lane];
                float wb1 = w_lds[(((pr1 >> 8) & 0xFFu) << 6) + lane];
                float wc1 = w_lds[(((pr1 >> 16) & 0xFFu) << 6) + lane];
                float wd1 = w_lds[(( pr1 >> 24        ) << 6) + lane];
                float wa2 = w_lds[((pr2       & 0xFFu) << 6) + lane];
                float wb2 = w_lds[(((pr2 >> 8) & 0xFFu) << 6) + lane];
                float wc2 = w_lds[(((pr2 >> 16) & 0xFFu) << 6) + lane];
                float wd2 = w_lds[(( pr2 >> 24        ) << 6) + lane];
                float s1 = (wa1 + wb1) + (wc1 + wd1);
                float s2 = (wa2 + wb2) + (wc2 + wd2);
                s2 = (q + 4 < k) ? s2 : 0.0f;                        // predicate 2nd chunk
                run += (double)s1;
                run += (double)s2;
            }
            A += (k + 3) & ~3;
            ser[t] = (float)run;
            bool cross_now = (tc == 127) && (run >= DTHRESH);
            if (cross_now) { tc = t; cvv = run; }            // cndmask, no branch
        }

        // cross-lane: e = min crossing time; winner = max cvv among tc==e, first-lane tie
        int e = tc;
        #pragma unroll
        for (int off = 32; off >= 1; off >>= 1) e = min(e, __shfl_xor(e, off));
        int wc = -1;
        double val = 0.0;
        if (e < 15) {                                    // uniform branch
            double vl = (tc == e) ? cvv : 0.0;
            double m = vl;
            #pragma unroll
            for (int off = 32; off >= 1; off >>= 1) m = fmax(m, __shfl_xor(m, off));
            unsigned long long mk = __ballot(vl == m);
            wc = __ffsll(mk) - 1;
            val = m;

            // winner's series -> lanes 0..14 via shfl, zero before crossing
            float ov = 0.0f;
            #pragma unroll
            for (int t = 0; t < 15; ++t) {
                float sv = __shfl(ser[t], wc);
                if (lane == t) ov = sv;
            }
            if (lane < e) ov = 0.0f;                     // monotone: below thresh before e
            if (lane < 15) series_ws[p * 16 + lane] = ov;
        }
        if (lane == 0) {
            winc_ws[p] = (int8_t)wc;
            nmap_ws[p] = (uint8_t)(wc >= 0 ? (15 - e) : 0);
            if (wc >= 0) val_ws[p] = val;
        }
    }
}

// ---------------- K3: cooperative 5-round k-winners (lexicographic key, 64 blocks) ----------------
// R3 version verbatim (known-good). Key = nm*2048 + val orders exactly as the
// reference's nm*(val + 15*max_val); 5 grid syncs total.
__global__ __launch_bounds__(256) void kwin_kernel(
        const int8_t* __restrict__ winc, const uint8_t* __restrict__ nmap,
        const double* __restrict__ val, float* __restrict__ outw,
        double* __restrict__ redv, unsigned* __restrict__ redi)
{
    cg::grid_group grid = cg::this_grid();
    const int tid  = threadIdx.x;
    const int bid  = blockIdx.x;
    const int lane = tid & 63, wvi = tid >> 6;

    __shared__ double   s_v[4];
    __shared__ unsigned s_i[4];

    int     pc[4];
    int     phh[4], pww[4];
    double  key[4];
    unsigned idx[4];
    bool    alive[4];
    #pragma unroll
    for (int k = 0; k < 4; ++k) {
        const int p = (k << 14) | (bid << 8) | tid;      // coalesced per k
        const int c = winc[p];
        alive[k] = (c >= 0);
        const double vp = alive[k] ? val[p] : 0.0;       // val only valid where winner exists
        key[k]  = (double)nmap[p] * 2048.0 + vp;         // lex (nm, val) in one double
        idx[k]  = ((unsigned)c << 16) | (unsigned)p;     // c-major flat index (tie-break)
        pc[k]   = c;
        phh[k]  = p >> 8;
        pww[k]  = p & 255;
    }

    for (int r = 0; r < 5; ++r) {
        __syncthreads();                          // protect s_v/s_i reuse across rounds
        const int par = r & 1;

        // best among my 4 positions (static indexing -> registers)
        double   bv = -1.0;
        unsigned bi = 0xFFFFFFFFu;
        #pragma unroll
        for (int k = 0; k < 4; ++k) {
            if (alive[k] && (key[k] > bv || (key[k] == bv && idx[k] < bi))) {
                bv = key[k]; bi = idx[k];
            }
        }
        // wave argmax with (key desc, fi asc) ordering
        #pragma unroll
        for (int off = 32; off >= 1; off >>= 1) {
            double   ov = __shfl_xor(bv, off);
            unsigned oi = __shfl_xor(bi, off);
            if (ov > bv || (ov == bv && oi < bi)) { bv = ov; bi = oi; }
        }
        if (lane == 0) { s_v[wvi] = bv; s_i[wvi] = bi; }
        __syncthreads();
        if (tid == 0) {
            double bbv = s_v[0]; unsigned bbi = s_i[0];
            #pragma unroll
            for (int i = 1; i < 4; ++i)
                if (s_v[i] > bbv || (s_v[i] == bbv && s_i[i] < bbi)) { bbv = s_v[i]; bbi = s_i[i]; }
            redv[par * 64 + bid] = bbv;
            redi[par * 64 + bid] = bbi;
        }
        grid.sync();

        // wave 0 of every block reduces the 64 partials -> identical winner everywhere
        if (wvi == 0) {
            double   gv = redv[par * 64 + lane];
            unsigned gi = redi[par * 64 + lane];
            #pragma unroll
            for (int off = 32; off >= 1; off >>= 1) {
                double   ov = __shfl_xor(gv, off);
                unsigned oi = __shfl_xor(gi, off);
                if (ov > gv || (ov == gv && oi < gi)) { gv = ov; gi = oi; }
            }
            if (lane == 0) { s_v[0] = gv; s_i[0] = gi; }
        }
        __syncthreads();
        const double   bbv = s_v[0];
        const unsigned bbi = s_i[0];

        const bool valid = (bbv > 0.0);          // any alive position has key >= 2048+15
        if (bid == 0 && tid == 0) {
            int wc2 = (int)(bbi >> 16), pp = (int)(bbi & 0xFFFFu);
            outw[r * 3 + 0] = valid ? (float)wc2       : -1.0f;
            outw[r * 3 + 1] = valid ? (float)(pp >> 8) : -1.0f;
            outw[r * 3 + 2] = valid ? (float)(pp & 255): -1.0f;
        }
        if (valid) {
            const int wc2 = (int)(bbi >> 16);
            const int wp  = (int)(bbi & 0xFFFFu);
            const int wh  = wp >> 8, wwv = wp & 255;
            #pragma unroll
            for (int k = 0; k < 4; ++k) {
                if (pc[k] == wc2 || (phh[k] >= wh - 3 && phh[k] <= wh + 3 &&
                                     pww[k] >= wwv - 3 && pww[k] <= wwv + 3)) alive[k] = false;
            }
        }
        // invalid round => all totals zero => later rounds invalid too (reference's
        // phantom kill of an all-zero total is inert for outputs)
    }
}

// ---------------- K4: expand winner map to full spk/pot (R3 verbatim; dense writes) ----------------
__global__ __launch_bounds__(256) void expand_kernel(
        const int8_t* __restrict__ winc, const float* __restrict__ series,
        float* __restrict__ spk, float* __restrict__ pot)
{
    int idx4 = blockIdx.x * 256 + threadIdx.x;   // < 15,728,640
    int w4 = idx4 & 63;
    int h  = (idx4 >> 6) & 255;
    int c  = (idx4 >> 14) & 63;
    int t  = idx4 >> 20;
    int pbase = h * W + (w4 << 2);
    uint32_t wcs = *reinterpret_cast<const uint32_t*>(winc + pbase);
    vfloat4 pv = (vfloat4)(0.0f);
    vfloat4 sv = (vfloat4)(0.0f);
    #pragma unroll
    for (int e2 = 0; e2 < 4; ++e2) {
        int8_t wcb = (int8_t)((wcs >> (8 * e2)) & 0xFFu);
        if ((int)wcb == c) {
            float xv = series[(size_t)(pbase + e2) * 16 + t];
            pv[e2] = xv;
            sv[e2] = (xv > 0.f) ? 1.0f : 0.0f;
        }
    }
    reinterpret_cast<vfloat4*>(spk)[idx4] = sv;
    reinterpret_cast<vfloat4*>(pot)[idx4] = pv;
}

extern "C" void kernel_launch(void* const* d_in, const int* in_sizes, int n_in,
                              void* d_out, int out_size, void* d_ws, size_t ws_size,
                              hipStream_t stream)
{
    if (ws_size < WS_NEED) return;

    const float* x  = (const float*)d_in[0];
    const float* w1 = (const float*)d_in[1];
    uint8_t* ws = (uint8_t*)d_ws;
    uint8_t* ftg    = ws + WS_FT;
    float*   series = (float*)(ws + WS_SERIES);
    int8_t*  winc   = (int8_t*)(ws + WS_WINC);
    uint8_t* nmap   = (uint8_t*)(ws + WS_NMAP);
    double*  val    = (double*)(ws + WS_VAL);
    double*  redv   = (double*)(ws + WS_RED);
    unsigned* redi  = (unsigned*)(ws + WS_RIX);

    float* spk  = (float*)d_out;
    float* pot  = spk + (size_t)T_STEPS * C_OUT * NPOS;
    float* outw = pot + (size_t)T_STEPS * C_OUT * NPOS;

    hipLaunchKernelGGL(ft_kernel,     dim3(1536),  dim3(256),  0, stream, x, ftg);
    hipLaunchKernelGGL(conv_kernel,   dim3(4096),  dim3(256),  0, stream, w1, ftg, series, winc, nmap, val);

    void* kargs[] = { (void*)&winc, (void*)&nmap, (void*)&val,
                      (void*)&outw, (void*)&redv, (void*)&redi };
    hipLaunchCooperativeKernel((const void*)kwin_kernel, dim3(64), dim3(256), kargs, 0, stream);

    hipLaunchKernelGGL(expand_kernel, dim3(61440), dim3(256),  0, stream, winc, series, spk, pot);
}

// Round 9
// 744.776 us; speedup vs baseline: 1.1568x; 1.0142x over previous
//
#include <hip/hip_runtime.h>
#include <hip/hip_cooperative_groups.h>
#include <stdint.h>

namespace cg = cooperative_groups;

static constexpr int T_STEPS = 15;
static constexpr int C_IN = 6;
static constexpr int C_OUT = 64;
static constexpr int H = 256;
static constexpr int W = 256;
static constexpr int NPOS = H * W;            // 65536
static constexpr int NTAP = 150;              // 6*5*5
#define DTHRESH 15.0

typedef float vfloat4 __attribute__((ext_vector_type(4)));

// workspace layout (bytes)
static constexpr size_t WS_FT     = 0;                              // uint8 [C_IN*NPOS]
static constexpr size_t WS_SERIES = 393216;                         // float [NPOS*16]
static constexpr size_t WS_WINC   = WS_SERIES + (size_t)NPOS*16*4;  // int8  [NPOS]
static constexpr size_t WS_NMAP   = WS_WINC + (size_t)NPOS;         // uint8 [NPOS]
static constexpr size_t WS_VAL    = WS_NMAP + (size_t)NPOS;         // double[NPOS]
static constexpr size_t WS_RED    = WS_VAL + (size_t)NPOS*8;        // double[128]: round partials par0/par1 (2x64)
static constexpr size_t WS_RIX    = WS_RED + 128*8;                 // uint32[128]: round indices par0/par1
static constexpr size_t WS_NEED   = WS_RIX + 128*4;

// ---------------- K1: first-spike-time map ----------------
__global__ __launch_bounds__(256) void ft_kernel(const float* __restrict__ x,
                                                 uint8_t* __restrict__ ft) {
    int i = blockIdx.x * 256 + threadIdx.x;
    if (i >= C_IN * NPOS) return;
    int f = 15;
    #pragma unroll
    for (int t = T_STEPS - 1; t >= 0; --t) {
        if (x[(size_t)t * (C_IN * NPOS) + i] > 0.0f) f = t;
    }
    ft[i] = (uint8_t)f;
}

// ---------------- K2: per-position conv-as-sorted-accumulate + pointwise WTA ----------------
// R8 version verbatim (measured == best-known within noise). Paired 8-tap chunks,
// zero-weight tap row + terminal pad word, fp32 pairwise + single fp64 accumulate.
// LDS: 38656 + 600 + 256 + 800 = 40312 B -> 4 blocks/CU.
__global__ __launch_bounds__(256, 4) void conv_kernel(
        const float* __restrict__ w1, const uint8_t* __restrict__ ftg,
        float* __restrict__ series_ws, int8_t* __restrict__ winc_ws,
        uint8_t* __restrict__ nmap_ws, double* __restrict__ val_ws)
{
    __shared__ float w_lds[(NTAP + 1) * 64];                 // [tap][o]; row 150 = zeros
    __shared__ uint8_t ft_lds[6 * 5 * 20];                   // [c][kh][col 0..19]
    __shared__ alignas(16) unsigned cnt_lds[4][16];          // per-wave
    __shared__ alignas(8) uint8_t sorted_lds[4][200];        // per-wave, 4-aligned buckets, u8 tap ids

    int tid = threadIdx.x;
    int bid = blockIdx.x;                        // 0..4095
    int h  = bid >> 4;
    int w0 = (bid & 15) << 4;

    // stage weights transposed: w_lds[tap*64 + o] = w1[o*150 + tap] (coalesced reads)
    for (int i = tid; i < C_OUT * NTAP; i += 256) {
        int o = i / NTAP;
        int tap = i - o * NTAP;
        w_lds[tap * 64 + o] = w1[i];
    }
    if (tid < 64) w_lds[NTAP * 64 + tid] = 0.0f;             // zero row for pad slots
    // stage ft tile with pad-of-15 (never spikes) outside the image
    for (int i = tid; i < 600; i += 256) {
        int c = i / 100;
        int r = i - c * 100;
        int kh = r / 20;
        int j  = r - kh * 20;
        int gh = h - 2 + kh;
        int gw = w0 - 2 + j;
        uint8_t v = 15;
        if (gh >= 0 && gh < H && gw >= 0 && gw < W) v = ftg[c * NPOS + gh * W + gw];
        ft_lds[(c * 5 + kh) * 20 + j] = v;
    }
    __syncthreads();   // the ONLY block barrier

    int lane = tid & 63;
    int wvi  = tid >> 6;
    unsigned* cnt = cnt_lds[wvi];
    uint8_t* srt = sorted_lds[wvi];

    for (int iter = 0; iter < 4; ++iter) {
        int xl = iter * 4 + wvi;                 // local col 0..15
        int p  = h * W + w0 + xl;

        if (lane < 16) cnt[lane] = 0;            // wave-private, no barrier

        // counting sort of the 150 taps by first-spike time (3 tap slots per lane)
        int tap0 = lane, tap1 = lane + 64, tap2 = lane + 128;
        auto ftv = [&](int tap) -> unsigned {
            int c = tap / 25;
            int r = tap - c * 25;
            int kh = r / 5;
            int kw = r - kh * 5;
            return ft_lds[(c * 5 + kh) * 20 + xl + kw];
        };
        unsigned f0 = ftv(tap0);
        unsigned f1 = ftv(tap1);
        unsigned f2 = (tap2 < NTAP) ? ftv(tap2) : 15u;
        unsigned r0 = 0, r1 = 0, r2 = 0;
        if (f0 < 15u) r0 = atomicAdd(&cnt[f0], 1u);
        if (f1 < 15u) r1 = atomicAdd(&cnt[f1], 1u);
        if (f2 < 15u) r2 = atomicAdd(&cnt[f2], 1u);

        // read all 16 counts via 4 vector loads (broadcast)
        uint4 c4[4];
        #pragma unroll
        for (int i = 0; i < 4; ++i) c4[i] = ((const uint4*)cnt)[i];
        unsigned cv_t[16];
        #pragma unroll
        for (int i = 0; i < 4; ++i) {
            cv_t[4*i+0] = c4[i].x; cv_t[4*i+1] = c4[i].y;
            cv_t[4*i+2] = c4[i].z; cv_t[4*i+3] = c4[i].w;
        }
        int kt[15];
        #pragma unroll
        for (int t = 0; t < 15; ++t) kt[t] = (int)__builtin_amdgcn_readfirstlane(cv_t[t]);

        // aligned-4 bucket starts: per-lane predicated prefix of align4(counts)
        unsigned st0 = 0, st1 = 0, st2 = 0, stp = 0;
        #pragma unroll
        for (int t = 0; t < 15; ++t) {
            unsigned a = (cv_t[t] + 3u) & ~3u;
            if ((unsigned)t < f0) st0 += a;
            if ((unsigned)t < f1) st1 += a;
            if ((unsigned)t < f2) st2 += a;
            if (t < lane) stp += a;              // pad-fill prefix for lane==t bucket; lane 15: total
        }
        if (f0 < 15u) srt[st0 + r0] = (uint8_t)tap0;
        if (f1 < 15u) srt[st1 + r1] = (uint8_t)tap1;
        if (f2 < 15u) srt[st2 + r2] = (uint8_t)tap2;

        // fill pad slots of bucket t=lane (lane<15) with tap 150 (zero weight)
        if (lane < 15) {
            unsigned kk = cnt[lane];             // final count for this bucket
            unsigned a4 = (kk + 3u) & ~3u;
            if (kk     < a4) srt[stp + kk]     = (uint8_t)NTAP;
            if (kk + 1 < a4) srt[stp + kk + 1] = (uint8_t)NTAP;
            if (kk + 2 < a4) srt[stp + kk + 2] = (uint8_t)NTAP;
        }
        // lane 15: terminal pad word at stp == total aligned size, so the
        // paired-chunk overread at A+q+4 always lands on valid tap ids
        if (lane == 15) {
            srt[stp]     = (uint8_t)NTAP;
            srt[stp + 1] = (uint8_t)NTAP;
            srt[stp + 2] = (uint8_t)NTAP;
            srt[stp + 3] = (uint8_t)NTAP;
        }

        // main accumulate: TWO chunks per iteration (8 taps). Both srt words and
        // all 8 w reads are address-independent -> issue together, latency overlaps.
        // fp64 order identical to R5: run += s1; run += s2(or exact 0.0).
        double run = 0.0, cvv = 0.0;
        int tc = 127;
        float ser[15];
        int A = 0;                               // aligned bucket start
        #pragma unroll
        for (int t = 0; t < 15; ++t) {
            int k = kt[t];
            for (int q = 0; q < k; q += 8) {
                unsigned pr1 = *(const unsigned*)(srt + A + q);      // chunk 1 (always valid)
                unsigned pr2 = *(const unsigned*)(srt + A + q + 4);  // chunk 2 or next-bucket/terminal pad
                float wa1 = w_lds[((pr1       & 0xFFu) << 6) + lane];
                float wb1 = w_lds[(((pr1 >> 8) & 0xFFu) << 6) + lane];
                float wc1 = w_lds[(((pr1 >> 16) & 0xFFu) << 6) + lane];
                float wd1 = w_lds[(( pr1 >> 24        ) << 6) + lane];
                float wa2 = w_lds[((pr2       & 0xFFu) << 6) + lane];
                float wb2 = w_lds[(((pr2 >> 8) & 0xFFu) << 6) + lane];
                float wc2 = w_lds[(((pr2 >> 16) & 0xFFu) << 6) + lane];
                float wd2 = w_lds[(( pr2 >> 24        ) << 6) + lane];
                float s1 = (wa1 + wb1) + (wc1 + wd1);
                float s2 = (wa2 + wb2) + (wc2 + wd2);
                s2 = (q + 4 < k) ? s2 : 0.0f;                        // predicate 2nd chunk
                run += (double)s1;
                run += (double)s2;
            }
            A += (k + 3) & ~3;
            ser[t] = (float)run;
            bool cross_now = (tc == 127) && (run >= DTHRESH);
            if (cross_now) { tc = t; cvv = run; }            // cndmask, no branch
        }

        // cross-lane: e = min crossing time; winner = max cvv among tc==e, first-lane tie
        int e = tc;
        #pragma unroll
        for (int off = 32; off >= 1; off >>= 1) e = min(e, __shfl_xor(e, off));
        int wc = -1;
        double val = 0.0;
        if (e < 15) {                                    // uniform branch
            double vl = (tc == e) ? cvv : 0.0;
            double m = vl;
            #pragma unroll
            for (int off = 32; off >= 1; off >>= 1) m = fmax(m, __shfl_xor(m, off));
            unsigned long long mk = __ballot(vl == m);
            wc = __ffsll(mk) - 1;
            val = m;

            // winner's series -> lanes 0..14 via shfl, zero before crossing
            float ov = 0.0f;
            #pragma unroll
            for (int t = 0; t < 15; ++t) {
                float sv = __shfl(ser[t], wc);
                if (lane == t) ov = sv;
            }
            if (lane < e) ov = 0.0f;                     // monotone: below thresh before e
            if (lane < 15) series_ws[p * 16 + lane] = ov;
        }
        if (lane == 0) {
            winc_ws[p] = (int8_t)wc;
            nmap_ws[p] = (uint8_t)(wc >= 0 ? (15 - e) : 0);
            if (wc >= 0) val_ws[p] = val;
        }
    }
}

// ---------------- K3: cooperative 5-round k-winners (lexicographic key, 64 blocks) ----------------
// R3 version verbatim (known-good). Key = nm*2048 + val orders exactly as the
// reference's nm*(val + 15*max_val); 5 grid syncs total.
__global__ __launch_bounds__(256) void kwin_kernel(
        const int8_t* __restrict__ winc, const uint8_t* __restrict__ nmap,
        const double* __restrict__ val, float* __restrict__ outw,
        double* __restrict__ redv, unsigned* __restrict__ redi)
{
    cg::grid_group grid = cg::this_grid();
    const int tid  = threadIdx.x;
    const int bid  = blockIdx.x;
    const int lane = tid & 63, wvi = tid >> 6;

    __shared__ double   s_v[4];
    __shared__ unsigned s_i[4];

    int     pc[4];
    int     phh[4], pww[4];
    double  key[4];
    unsigned idx[4];
    bool    alive[4];
    #pragma unroll
    for (int k = 0; k < 4; ++k) {
        const int p = (k << 14) | (bid << 8) | tid;      // coalesced per k
        const int c = winc[p];
        alive[k] = (c >= 0);
        const double vp = alive[k] ? val[p] : 0.0;       // val only valid where winner exists
        key[k]  = (double)nmap[p] * 2048.0 + vp;         // lex (nm, val) in one double
        idx[k]  = ((unsigned)c << 16) | (unsigned)p;     // c-major flat index (tie-break)
        pc[k]   = c;
        phh[k]  = p >> 8;
        pww[k]  = p & 255;
    }

    for (int r = 0; r < 5; ++r) {
        __syncthreads();                          // protect s_v/s_i reuse across rounds
        const int par = r & 1;

        // best among my 4 positions (static indexing -> registers)
        double   bv = -1.0;
        unsigned bi = 0xFFFFFFFFu;
        #pragma unroll
        for (int k = 0; k < 4; ++k) {
            if (alive[k] && (key[k] > bv || (key[k] == bv && idx[k] < bi))) {
                bv = key[k]; bi = idx[k];
            }
        }
        // wave argmax with (key desc, fi asc) ordering
        #pragma unroll
        for (int off = 32; off >= 1; off >>= 1) {
            double   ov = __shfl_xor(bv, off);
            unsigned oi = __shfl_xor(bi, off);
            if (ov > bv || (ov == bv && oi < bi)) { bv = ov; bi = oi; }
        }
        if (lane == 0) { s_v[wvi] = bv; s_i[wvi] = bi; }
        __syncthreads();
        if (tid == 0) {
            double bbv = s_v[0]; unsigned bbi = s_i[0];
            #pragma unroll
            for (int i = 1; i < 4; ++i)
                if (s_v[i] > bbv || (s_v[i] == bbv && s_i[i] < bbi)) { bbv = s_v[i]; bbi = s_i[i]; }
            redv[par * 64 + bid] = bbv;
            redi[par * 64 + bid] = bbi;
        }
        grid.sync();

        // wave 0 of every block reduces the 64 partials -> identical winner everywhere
        if (wvi == 0) {
            double   gv = redv[par * 64 + lane];
            unsigned gi = redi[par * 64 + lane];
            #pragma unroll
            for (int off = 32; off >= 1; off >>= 1) {
                double   ov = __shfl_xor(gv, off);
                unsigned oi = __shfl_xor(gi, off);
                if (ov > gv || (ov == gv && oi < gi)) { gv = ov; gi = oi; }
            }
            if (lane == 0) { s_v[0] = gv; s_i[0] = gi; }
        }
        __syncthreads();
        const double   bbv = s_v[0];
        const unsigned bbi = s_i[0];

        const bool valid = (bbv > 0.0);          // any alive position has key >= 2048+15
        if (bid == 0 && tid == 0) {
            int wc2 = (int)(bbi >> 16), pp = (int)(bbi & 0xFFFFu);
            outw[r * 3 + 0] = valid ? (float)wc2       : -1.0f;
            outw[r * 3 + 1] = valid ? (float)(pp >> 8) : -1.0f;
            outw[r * 3 + 2] = valid ? (float)(pp & 255): -1.0f;
        }
        if (valid) {
            const int wc2 = (int)(bbi >> 16);
            const int wp  = (int)(bbi & 0xFFFFu);
            const int wh  = wp >> 8, wwv = wp & 255;
            #pragma unroll
            for (int k = 0; k < 4; ++k) {
                if (pc[k] == wc2 || (phh[k] >= wh - 3 && phh[k] <= wh + 3 &&
                                     pww[k] >= wwv - 3 && pww[k] <= wwv + 3)) alive[k] = false;
            }
        }
        // invalid round => all totals zero => later rounds invalid too (reference's
        // phantom kill of an all-zero total is inert for outputs)
    }
}

// ---------------- K4: expand winner map to full spk/pot (NON-TEMPORAL stores) ----------------
// Same structure as R3's dense expand; the two 503 MB one-touch store streams are
// marked non-temporal (nt-flagged global_store_dwordx4) to bypass L2 write-allocate,
// leaving L2 for the reused winc (63 MB of broadcast reads) and series gathers.
__global__ __launch_bounds__(256) void expand_kernel(
        const int8_t* __restrict__ winc, const float* __restrict__ series,
        float* __restrict__ spk, float* __restrict__ pot)
{
    int idx4 = blockIdx.x * 256 + threadIdx.x;   // < 15,728,640
    int w4 = idx4 & 63;
    int h  = (idx4 >> 6) & 255;
    int c  = (idx4 >> 14) & 63;
    int t  = idx4 >> 20;
    int pbase = h * W + (w4 << 2);
    uint32_t wcs = *reinterpret_cast<const uint32_t*>(winc + pbase);
    vfloat4 pv = (vfloat4)(0.0f);
    vfloat4 sv = (vfloat4)(0.0f);
    #pragma unroll
    for (int e2 = 0; e2 < 4; ++e2) {
        int8_t wcb = (int8_t)((wcs >> (8 * e2)) & 0xFFu);
        if ((int)wcb == c) {
            float xv = series[(size_t)(pbase + e2) * 16 + t];
            pv[e2] = xv;
            sv[e2] = (xv > 0.f) ? 1.0f : 0.0f;
        }
    }
    __builtin_nontemporal_store(sv, reinterpret_cast<vfloat4*>(spk) + idx4);
    __builtin_nontemporal_store(pv, reinterpret_cast<vfloat4*>(pot) + idx4);
}

extern "C" void kernel_launch(void* const* d_in, const int* in_sizes, int n_in,
                              void* d_out, int out_size, void* d_ws, size_t ws_size,
                              hipStream_t stream)
{
    if (ws_size < WS_NEED) return;

    const float* x  = (const float*)d_in[0];
    const float* w1 = (const float*)d_in[1];
    uint8_t* ws = (uint8_t*)d_ws;
    uint8_t* ftg    = ws + WS_FT;
    float*   series = (float*)(ws + WS_SERIES);
    int8_t*  winc   = (int8_t*)(ws + WS_WINC);
    uint8_t* nmap   = (uint8_t*)(ws + WS_NMAP);
    double*  val    = (double*)(ws + WS_VAL);
    double*  redv   = (double*)(ws + WS_RED);
    unsigned* redi  = (unsigned*)(ws + WS_RIX);

    float* spk  = (float*)d_out;
    float* pot  = spk + (size_t)T_STEPS * C_OUT * NPOS;
    float* outw = pot + (size_t)T_STEPS * C_OUT * NPOS;

    hipLaunchKernelGGL(ft_kernel,     dim3(1536),  dim3(256),  0, stream, x, ftg);
    hipLaunchKernelGGL(conv_kernel,   dim3(4096),  dim3(256),  0, stream, w1, ftg, series, winc, nmap, val);

    void* kargs[] = { (void*)&winc, (void*)&nmap, (void*)&val,
                      (void*)&outw, (void*)&redv, (void*)&redi };
    hipLaunchCooperativeKernel((const void*)kwin_kernel, dim3(64), dim3(256), kargs, 0, stream);

    hipLaunchKernelGGL(expand_kernel, dim3(61440), dim3(256),  0, stream, winc, series, spk, pot);
}

// Round 10
// 737.273 us; speedup vs baseline: 1.1686x; 1.0102x over previous
//
#include <hip/hip_runtime.h>
#include <hip/hip_cooperative_groups.h>
#include <stdint.h>

namespace cg = cooperative_groups;

static constexpr int T_STEPS = 15;
static constexpr int C_IN = 6;
static constexpr int C_OUT = 64;
static constexpr int H = 256;
static constexpr int W = 256;
static constexpr int NPOS = H * W;            // 65536
static constexpr int NTAP = 150;              // 6*5*5
#define DTHRESH_F 15.0f

typedef float vfloat4 __attribute__((ext_vector_type(4)));

// workspace layout (bytes)
static constexpr size_t WS_FT     = 0;                              // uint8 [C_IN*NPOS]
static constexpr size_t WS_SERIES = 393216;                         // float [NPOS*16]
static constexpr size_t WS_WINC   = WS_SERIES + (size_t)NPOS*16*4;  // int8  [NPOS]
static constexpr size_t WS_NMAP   = WS_WINC + (size_t)NPOS;         // uint8 [NPOS]
static constexpr size_t WS_VAL    = WS_NMAP + (size_t)NPOS;         // double[NPOS]
static constexpr size_t WS_RED    = WS_VAL + (size_t)NPOS*8;        // double[128]: round partials par0/par1 (2x64)
static constexpr size_t WS_RIX    = WS_RED + 128*8;                 // uint32[128]: round indices par0/par1
static constexpr size_t WS_NEED   = WS_RIX + 128*4;

// ---------------- K1: first-spike-time map ----------------
__global__ __launch_bounds__(256) void ft_kernel(const float* __restrict__ x,
                                                 uint8_t* __restrict__ ft) {
    int i = blockIdx.x * 256 + threadIdx.x;
    if (i >= C_IN * NPOS) return;
    int f = 15;
    #pragma unroll
    for (int t = T_STEPS - 1; t >= 0; --t) {
        if (x[(size_t)t * (C_IN * NPOS) + i] > 0.0f) f = t;
    }
    ft[i] = (uint8_t)f;
}

// ---------------- K2: per-position conv-as-sorted-accumulate + pointwise WTA ----------------
// R9 structure with PURE-FP32 accumulation (fp64 removed from the inner loop and
// epilogue; only the final val_ws write casts to double for kwin). Removes
// 2x v_cvt_f64_f32 + 2x v_add_f64 (~16 of ~60 VALU cyc) per 8-tap iteration and
// halves the epilogue shuffle-reduce cost. fp32 running sum to ~120 over <=38
// adds: ~1e-5 abs error, at/below the reference's own fp32 conv rounding scale;
// threshold compare run >= 15.0f now matches the reference's fp32 semantics.
// LDS: 38656 + 600 + 256 + 800 = 40312 B -> 4 blocks/CU.
__global__ __launch_bounds__(256, 4) void conv_kernel(
        const float* __restrict__ w1, const uint8_t* __restrict__ ftg,
        float* __restrict__ series_ws, int8_t* __restrict__ winc_ws,
        uint8_t* __restrict__ nmap_ws, double* __restrict__ val_ws)
{
    __shared__ float w_lds[(NTAP + 1) * 64];                 // [tap][o]; row 150 = zeros
    __shared__ uint8_t ft_lds[6 * 5 * 20];                   // [c][kh][col 0..19]
    __shared__ alignas(16) unsigned cnt_lds[4][16];          // per-wave
    __shared__ alignas(8) uint8_t sorted_lds[4][200];        // per-wave, 4-aligned buckets, u8 tap ids

    int tid = threadIdx.x;
    int bid = blockIdx.x;                        // 0..4095
    int h  = bid >> 4;
    int w0 = (bid & 15) << 4;

    // stage weights transposed: w_lds[tap*64 + o] = w1[o*150 + tap] (coalesced reads)
    for (int i = tid; i < C_OUT * NTAP; i += 256) {
        int o = i / NTAP;
        int tap = i - o * NTAP;
        w_lds[tap * 64 + o] = w1[i];
    }
    if (tid < 64) w_lds[NTAP * 64 + tid] = 0.0f;             // zero row for pad slots
    // stage ft tile with pad-of-15 (never spikes) outside the image
    for (int i = tid; i < 600; i += 256) {
        int c = i / 100;
        int r = i - c * 100;
        int kh = r / 20;
        int j  = r - kh * 20;
        int gh = h - 2 + kh;
        int gw = w0 - 2 + j;
        uint8_t v = 15;
        if (gh >= 0 && gh < H && gw >= 0 && gw < W) v = ftg[c * NPOS + gh * W + gw];
        ft_lds[(c * 5 + kh) * 20 + j] = v;
    }
    __syncthreads();   // the ONLY block barrier

    int lane = tid & 63;
    int wvi  = tid >> 6;
    unsigned* cnt = cnt_lds[wvi];
    uint8_t* srt = sorted_lds[wvi];

    for (int iter = 0; iter < 4; ++iter) {
        int xl = iter * 4 + wvi;                 // local col 0..15
        int p  = h * W + w0 + xl;

        if (lane < 16) cnt[lane] = 0;            // wave-private, no barrier

        // counting sort of the 150 taps by first-spike time (3 tap slots per lane)
        int tap0 = lane, tap1 = lane + 64, tap2 = lane + 128;
        auto ftv = [&](int tap) -> unsigned {
            int c = tap / 25;
            int r = tap - c * 25;
            int kh = r / 5;
            int kw = r - kh * 5;
            return ft_lds[(c * 5 + kh) * 20 + xl + kw];
        };
        unsigned f0 = ftv(tap0);
        unsigned f1 = ftv(tap1);
        unsigned f2 = (tap2 < NTAP) ? ftv(tap2) : 15u;
        unsigned r0 = 0, r1 = 0, r2 = 0;
        if (f0 < 15u) r0 = atomicAdd(&cnt[f0], 1u);
        if (f1 < 15u) r1 = atomicAdd(&cnt[f1], 1u);
        if (f2 < 15u) r2 = atomicAdd(&cnt[f2], 1u);

        // read all 16 counts via 4 vector loads (broadcast)
        uint4 c4[4];
        #pragma unroll
        for (int i = 0; i < 4; ++i) c4[i] = ((const uint4*)cnt)[i];
        unsigned cv_t[16];
        #pragma unroll
        for (int i = 0; i < 4; ++i) {
            cv_t[4*i+0] = c4[i].x; cv_t[4*i+1] = c4[i].y;
            cv_t[4*i+2] = c4[i].z; cv_t[4*i+3] = c4[i].w;
        }
        int kt[15];
        #pragma unroll
        for (int t = 0; t < 15; ++t) kt[t] = (int)__builtin_amdgcn_readfirstlane(cv_t[t]);

        // aligned-4 bucket starts: per-lane predicated prefix of align4(counts)
        unsigned st0 = 0, st1 = 0, st2 = 0, stp = 0;
        #pragma unroll
        for (int t = 0; t < 15; ++t) {
            unsigned a = (cv_t[t] + 3u) & ~3u;
            if ((unsigned)t < f0) st0 += a;
            if ((unsigned)t < f1) st1 += a;
            if ((unsigned)t < f2) st2 += a;
            if (t < lane) stp += a;              // pad-fill prefix for lane==t bucket; lane 15: total
        }
        if (f0 < 15u) srt[st0 + r0] = (uint8_t)tap0;
        if (f1 < 15u) srt[st1 + r1] = (uint8_t)tap1;
        if (f2 < 15u) srt[st2 + r2] = (uint8_t)tap2;

        // fill pad slots of bucket t=lane (lane<15) with tap 150 (zero weight)
        if (lane < 15) {
            unsigned kk = cnt[lane];             // final count for this bucket
            unsigned a4 = (kk + 3u) & ~3u;
            if (kk     < a4) srt[stp + kk]     = (uint8_t)NTAP;
            if (kk + 1 < a4) srt[stp + kk + 1] = (uint8_t)NTAP;
            if (kk + 2 < a4) srt[stp + kk + 2] = (uint8_t)NTAP;
        }
        // lane 15: terminal pad word at stp == total aligned size, so the
        // paired-chunk overread at A+q+4 always lands on valid tap ids
        if (lane == 15) {
            srt[stp]     = (uint8_t)NTAP;
            srt[stp + 1] = (uint8_t)NTAP;
            srt[stp + 2] = (uint8_t)NTAP;
            srt[stp + 3] = (uint8_t)NTAP;
        }

        // main accumulate: TWO chunks per iteration (8 taps), pure fp32.
        // Both srt words and all 8 w reads are address-independent.
        float run = 0.0f, cvv = 0.0f;
        int tc = 127;
        float ser[15];
        int A = 0;                               // aligned bucket start
        #pragma unroll
        for (int t = 0; t < 15; ++t) {
            int k = kt[t];
            for (int q = 0; q < k; q += 8) {
                unsigned pr1 = *(const unsigned*)(srt + A + q);      // chunk 1 (always valid)
                unsigned pr2 = *(const unsigned*)(srt + A + q + 4);  // chunk 2 or next-bucket/terminal pad
                float wa1 = w_lds[((pr1       & 0xFFu) << 6) + lane];
                float wb1 = w_lds[(((pr1 >> 8) & 0xFFu) << 6) + lane];
                float wc1 = w_lds[(((pr1 >> 16) & 0xFFu) << 6) + lane];
                float wd1 = w_lds[(( pr1 >> 24        ) << 6) + lane];
                float wa2 = w_lds[((pr2       & 0xFFu) << 6) + lane];
                float wb2 = w_lds[(((pr2 >> 8) & 0xFFu) << 6) + lane];
                float wc2 = w_lds[(((pr2 >> 16) & 0xFFu) << 6) + lane];
                float wd2 = w_lds[(( pr2 >> 24        ) << 6) + lane];
                float s1 = (wa1 + wb1) + (wc1 + wd1);
                float s2 = (wa2 + wb2) + (wc2 + wd2);
                s2 = (q + 4 < k) ? s2 : 0.0f;                        // predicate 2nd chunk
                run += (s1 + s2);
            }
            A += (k + 3) & ~3;
            ser[t] = run;
            bool cross_now = (tc == 127) && (run >= DTHRESH_F);
            if (cross_now) { tc = t; cvv = run; }            // cndmask, no branch
        }

        // cross-lane: e = min crossing time; winner = max cvv among tc==e, first-lane tie
        int e = tc;
        #pragma unroll
        for (int off = 32; off >= 1; off >>= 1) e = min(e, __shfl_xor(e, off));
        int wc = -1;
        float val = 0.0f;
        if (e < 15) {                                    // uniform branch
            float vl = (tc == e) ? cvv : 0.0f;
            float m = vl;
            #pragma unroll
            for (int off = 32; off >= 1; off >>= 1) m = fmaxf(m, __shfl_xor(m, off));
            unsigned long long mk = __ballot(vl == m);
            wc = __ffsll(mk) - 1;
            val = m;

            // winner's series -> lanes 0..14 via shfl, zero before crossing
            float ov = 0.0f;
            #pragma unroll
            for (int t = 0; t < 15; ++t) {
                float sv = __shfl(ser[t], wc);
                if (lane == t) ov = sv;
            }
            if (lane < e) ov = 0.0f;                     // monotone: below thresh before e
            if (lane < 15) series_ws[p * 16 + lane] = ov;
        }
        if (lane == 0) {
            winc_ws[p] = (int8_t)wc;
            nmap_ws[p] = (uint8_t)(wc >= 0 ? (15 - e) : 0);
            if (wc >= 0) val_ws[p] = (double)val;        // kwin consumes double
        }
    }
}

// ---------------- K3: cooperative 5-round k-winners (lexicographic key, 64 blocks) ----------------
// R3 version verbatim (known-good). Key = nm*2048 + val orders exactly as the
// reference's nm*(val + 15*max_val); 5 grid syncs total.
__global__ __launch_bounds__(256) void kwin_kernel(
        const int8_t* __restrict__ winc, const uint8_t* __restrict__ nmap,
        const double* __restrict__ val, float* __restrict__ outw,
        double* __restrict__ redv, unsigned* __restrict__ redi)
{
    cg::grid_group grid = cg::this_grid();
    const int tid  = threadIdx.x;
    const int bid  = blockIdx.x;
    const int lane = tid & 63, wvi = tid >> 6;

    __shared__ double   s_v[4];
    __shared__ unsigned s_i[4];

    int     pc[4];
    int     phh[4], pww[4];
    double  key[4];
    unsigned idx[4];
    bool    alive[4];
    #pragma unroll
    for (int k = 0; k < 4; ++k) {
        const int p = (k << 14) | (bid << 8) | tid;      // coalesced per k
        const int c = winc[p];
        alive[k] = (c >= 0);
        const double vp = alive[k] ? val[p] : 0.0;       // val only valid where winner exists
        key[k]  = (double)nmap[p] * 2048.0 + vp;         // lex (nm, val) in one double
        idx[k]  = ((unsigned)c << 16) | (unsigned)p;     // c-major flat index (tie-break)
        pc[k]   = c;
        phh[k]  = p >> 8;
        pww[k]  = p & 255;
    }

    for (int r = 0; r < 5; ++r) {
        __syncthreads();                          // protect s_v/s_i reuse across rounds
        const int par = r & 1;

        // best among my 4 positions (static indexing -> registers)
        double   bv = -1.0;
        unsigned bi = 0xFFFFFFFFu;
        #pragma unroll
        for (int k = 0; k < 4; ++k) {
            if (alive[k] && (key[k] > bv || (key[k] == bv && idx[k] < bi))) {
                bv = key[k]; bi = idx[k];
            }
        }
        // wave argmax with (key desc, fi asc) ordering
        #pragma unroll
        for (int off = 32; off >= 1; off >>= 1) {
            double   ov = __shfl_xor(bv, off);
            unsigned oi = __shfl_xor(bi, off);
            if (ov > bv || (ov == bv && oi < bi)) { bv = ov; bi = oi; }
        }
        if (lane == 0) { s_v[wvi] = bv; s_i[wvi] = bi; }
        __syncthreads();
        if (tid == 0) {
            double bbv = s_v[0]; unsigned bbi = s_i[0];
            #pragma unroll
            for (int i = 1; i < 4; ++i)
                if (s_v[i] > bbv || (s_v[i] == bbv && s_i[i] < bbi)) { bbv = s_v[i]; bbi = s_i[i]; }
            redv[par * 64 + bid] = bbv;
            redi[par * 64 + bid] = bbi;
        }
        grid.sync();

        // wave 0 of every block reduces the 64 partials -> identical winner everywhere
        if (wvi == 0) {
            double   gv = redv[par * 64 + lane];
            unsigned gi = redi[par * 64 + lane];
            #pragma unroll
            for (int off = 32; off >= 1; off >>= 1) {
                double   ov = __shfl_xor(gv, off);
                unsigned oi = __shfl_xor(gi, off);
                if (ov > gv || (ov == gv && oi < gi)) { gv = ov; gi = oi; }
            }
            if (lane == 0) { s_v[0] = gv; s_i[0] = gi; }
        }
        __syncthreads();
        const double   bbv = s_v[0];
        const unsigned bbi = s_i[0];

        const bool valid = (bbv > 0.0);          // any alive position has key >= 2048+15
        if (bid == 0 && tid == 0) {
            int wc2 = (int)(bbi >> 16), pp = (int)(bbi & 0xFFFFu);
            outw[r * 3 + 0] = valid ? (float)wc2       : -1.0f;
            outw[r * 3 + 1] = valid ? (float)(pp >> 8) : -1.0f;
            outw[r * 3 + 2] = valid ? (float)(pp & 255): -1.0f;
        }
        if (valid) {
            const int wc2 = (int)(bbi >> 16);
            const int wp  = (int)(bbi & 0xFFFFu);
            const int wh  = wp >> 8, wwv = wp & 255;
            #pragma unroll
            for (int k = 0; k < 4; ++k) {
                if (pc[k] == wc2 || (phh[k] >= wh - 3 && phh[k] <= wh + 3 &&
                                     pww[k] >= wwv - 3 && pww[k] <= wwv + 3)) alive[k] = false;
            }
        }
        // invalid round => all totals zero => later rounds invalid too (reference's
        // phantom kill of an all-zero total is inert for outputs)
    }
}

// ---------------- K4: expand winner map to full spk/pot (NON-TEMPORAL stores) ----------------
// R9 version verbatim (best measured): nt-flagged dwordx4 stores bypass L2
// write-allocate for the two 503 MB one-touch streams.
__global__ __launch_bounds__(256) void expand_kernel(
        const int8_t* __restrict__ winc, const float* __restrict__ series,
        float* __restrict__ spk, float* __restrict__ pot)
{
    int idx4 = blockIdx.x * 256 + threadIdx.x;   // < 15,728,640
    int w4 = idx4 & 63;
    int h  = (idx4 >> 6) & 255;
    int c  = (idx4 >> 14) & 63;
    int t  = idx4 >> 20;
    int pbase = h * W + (w4 << 2);
    uint32_t wcs = *reinterpret_cast<const uint32_t*>(winc + pbase);
    vfloat4 pv = (vfloat4)(0.0f);
    vfloat4 sv = (vfloat4)(0.0f);
    #pragma unroll
    for (int e2 = 0; e2 < 4; ++e2) {
        int8_t wcb = (int8_t)((wcs >> (8 * e2)) & 0xFFu);
        if ((int)wcb == c) {
            float xv = series[(size_t)(pbase + e2) * 16 + t];
            pv[e2] = xv;
            sv[e2] = (xv > 0.f) ? 1.0f : 0.0f;
        }
    }
    __builtin_nontemporal_store(sv, reinterpret_cast<vfloat4*>(spk) + idx4);
    __builtin_nontemporal_store(pv, reinterpret_cast<vfloat4*>(pot) + idx4);
}

extern "C" void kernel_launch(void* const* d_in, const int* in_sizes, int n_in,
                              void* d_out, int out_size, void* d_ws, size_t ws_size,
                              hipStream_t stream)
{
    if (ws_size < WS_NEED) return;

    const float* x  = (const float*)d_in[0];
    const float* w1 = (const float*)d_in[1];
    uint8_t* ws = (uint8_t*)d_ws;
    uint8_t* ftg    = ws + WS_FT;
    float*   series = (float*)(ws + WS_SERIES);
    int8_t*  winc   = (int8_t*)(ws + WS_WINC);
    uint8_t* nmap   = (uint8_t*)(ws + WS_NMAP);
    double*  val    = (double*)(ws + WS_VAL);
    double*  redv   = (double*)(ws + WS_RED);
    unsigned* redi  = (unsigned*)(ws + WS_RIX);

    float* spk  = (float*)d_out;
    float* pot  = spk + (size_t)T_STEPS * C_OUT * NPOS;
    float* outw = pot + (size_t)T_STEPS * C_OUT * NPOS;

    hipLaunchKernelGGL(ft_kernel,     dim3(1536),  dim3(256),  0, stream, x, ftg);
    hipLaunchKernelGGL(conv_kernel,   dim3(4096),  dim3(256),  0, stream, w1, ftg, series, winc, nmap, val);

    void* kargs[] = { (void*)&winc, (void*)&nmap, (void*)&val,
                      (void*)&outw, (void*)&redv, (void*)&redi };
    hipLaunchCooperativeKernel((const void*)kwin_kernel, dim3(64), dim3(256), kargs, 0, stream);

    hipLaunchKernelGGL(expand_kernel, dim3(61440), dim3(256),  0, stream, winc, series, spk, pot);
}

// Round 11
// 696.907 us; speedup vs baseline: 1.2363x; 1.0579x over previous
//
#include <hip/hip_runtime.h>
#include <hip/hip_cooperative_groups.h>
#include <stdint.h>

namespace cg = cooperative_groups;

static constexpr int T_STEPS = 15;
static constexpr int C_IN = 6;
static constexpr int C_OUT = 64;
static constexpr int H = 256;
static constexpr int W = 256;
static constexpr int NPOS = H * W;            // 65536
static constexpr int NTAP = 150;              // 6*5*5
#define DTHRESH_F 15.0f

typedef float vfloat4 __attribute__((ext_vector_type(4)));

// workspace layout (bytes)
static constexpr size_t WS_FT     = 0;                              // uint8 [C_IN*NPOS]
static constexpr size_t WS_SERIES = 393216;                         // float [NPOS*16]
static constexpr size_t WS_WINC   = WS_SERIES + (size_t)NPOS*16*4;  // int8  [NPOS]
static constexpr size_t WS_NMAP   = WS_WINC + (size_t)NPOS;         // uint8 [NPOS]
static constexpr size_t WS_VAL    = WS_NMAP + (size_t)NPOS;         // double[NPOS]
static constexpr size_t WS_RED    = WS_VAL + (size_t)NPOS*8;        // double[128]: round partials par0/par1 (2x64)
static constexpr size_t WS_RIX    = WS_RED + 128*8;                 // uint32[128]: round indices par0/par1
static constexpr size_t WS_NEED   = WS_RIX + 128*4;

// ---------------- K1: first-spike-time map ----------------
__global__ __launch_bounds__(256) void ft_kernel(const float* __restrict__ x,
                                                 uint8_t* __restrict__ ft) {
    int i = blockIdx.x * 256 + threadIdx.x;
    if (i >= C_IN * NPOS) return;
    int f = 15;
    #pragma unroll
    for (int t = T_STEPS - 1; t >= 0; --t) {
        if (x[(size_t)t * (C_IN * NPOS) + i] > 0.0f) f = t;
    }
    ft[i] = (uint8_t)f;
}

// ---------------- K2: per-position conv-as-sorted-accumulate + pointwise WTA ----------------
// R10 per-wave code VERBATIM; block geometry only: 512 threads = 8 waves sharing
// ONE w_lds copy (the dominant 38.7 KB LDS consumer), each wave runs the same
// 4-position iter loop -> 32 positions/block, 2048 blocks. LDS: 38656 + 1080(ft,
// 36 cols) + 512(cnt) + 1632(srt) = 41880 B -> 3 blocks/CU = 24 waves/CU =
// 6 waves/SIMD (1.5x latency hiding) if VGPR <= 85; lb(512,4) caps at 128 (no
// allocator squeeze - R6's spill trap avoided). w1 staging traffic halves.
__global__ __launch_bounds__(512, 4) void conv_kernel(
        const float* __restrict__ w1, const uint8_t* __restrict__ ftg,
        float* __restrict__ series_ws, int8_t* __restrict__ winc_ws,
        uint8_t* __restrict__ nmap_ws, double* __restrict__ val_ws)
{
    __shared__ float w_lds[(NTAP + 1) * 64];                 // [tap][o]; row 150 = zeros
    __shared__ uint8_t ft_lds[6 * 5 * 36];                   // [c][kh][col 0..35]
    __shared__ alignas(16) unsigned cnt_lds[8][16];          // per-wave
    __shared__ alignas(8) uint8_t sorted_lds[8][204];        // per-wave, 4-aligned buckets + pad

    int tid = threadIdx.x;
    int bid = blockIdx.x;                        // 0..2047
    int h  = bid >> 3;
    int w0 = (bid & 7) << 5;

    // stage weights transposed: w_lds[tap*64 + o] = w1[o*150 + tap] (coalesced reads)
    for (int i = tid; i < C_OUT * NTAP; i += 512) {
        int o = i / NTAP;
        int tap = i - o * NTAP;
        w_lds[tap * 64 + o] = w1[i];
    }
    if (tid < 64) w_lds[NTAP * 64 + tid] = 0.0f;             // zero row for pad slots
    // stage ft tile with pad-of-15 (never spikes) outside the image
    for (int i = tid; i < 1080; i += 512) {
        int c = i / 180;
        int r = i - c * 180;
        int kh = r / 36;
        int j  = r - kh * 36;
        int gh = h - 2 + kh;
        int gw = w0 - 2 + j;
        uint8_t v = 15;
        if (gh >= 0 && gh < H && gw >= 0 && gw < W) v = ftg[c * NPOS + gh * W + gw];
        ft_lds[(c * 5 + kh) * 36 + j] = v;
    }
    __syncthreads();   // the ONLY block barrier

    int lane = tid & 63;
    int wvi  = tid >> 6;                         // 0..7
    unsigned* cnt = cnt_lds[wvi];
    uint8_t* srt = sorted_lds[wvi];

    for (int iter = 0; iter < 4; ++iter) {
        int xl = iter * 8 + wvi;                 // local col 0..31
        int p  = h * W + w0 + xl;

        if (lane < 16) cnt[lane] = 0;            // wave-private, no barrier

        // counting sort of the 150 taps by first-spike time (3 tap slots per lane)
        int tap0 = lane, tap1 = lane + 64, tap2 = lane + 128;
        auto ftv = [&](int tap) -> unsigned {
            int c = tap / 25;
            int r = tap - c * 25;
            int kh = r / 5;
            int kw = r - kh * 5;
            return ft_lds[(c * 5 + kh) * 36 + xl + kw];
        };
        unsigned f0 = ftv(tap0);
        unsigned f1 = ftv(tap1);
        unsigned f2 = (tap2 < NTAP) ? ftv(tap2) : 15u;
        unsigned r0 = 0, r1 = 0, r2 = 0;
        if (f0 < 15u) r0 = atomicAdd(&cnt[f0], 1u);
        if (f1 < 15u) r1 = atomicAdd(&cnt[f1], 1u);
        if (f2 < 15u) r2 = atomicAdd(&cnt[f2], 1u);

        // read all 16 counts via 4 vector loads (broadcast)
        uint4 c4[4];
        #pragma unroll
        for (int i = 0; i < 4; ++i) c4[i] = ((const uint4*)cnt)[i];
        unsigned cv_t[16];
        #pragma unroll
        for (int i = 0; i < 4; ++i) {
            cv_t[4*i+0] = c4[i].x; cv_t[4*i+1] = c4[i].y;
            cv_t[4*i+2] = c4[i].z; cv_t[4*i+3] = c4[i].w;
        }
        int kt[15];
        #pragma unroll
        for (int t = 0; t < 15; ++t) kt[t] = (int)__builtin_amdgcn_readfirstlane(cv_t[t]);

        // aligned-4 bucket starts: per-lane predicated prefix of align4(counts)
        unsigned st0 = 0, st1 = 0, st2 = 0, stp = 0;
        #pragma unroll
        for (int t = 0; t < 15; ++t) {
            unsigned a = (cv_t[t] + 3u) & ~3u;
            if ((unsigned)t < f0) st0 += a;
            if ((unsigned)t < f1) st1 += a;
            if ((unsigned)t < f2) st2 += a;
            if (t < lane) stp += a;              // pad-fill prefix for lane==t bucket; lane 15: total
        }
        if (f0 < 15u) srt[st0 + r0] = (uint8_t)tap0;
        if (f1 < 15u) srt[st1 + r1] = (uint8_t)tap1;
        if (f2 < 15u) srt[st2 + r2] = (uint8_t)tap2;

        // fill pad slots of bucket t=lane (lane<15) with tap 150 (zero weight)
        if (lane < 15) {
            unsigned kk = cnt[lane];             // final count for this bucket
            unsigned a4 = (kk + 3u) & ~3u;
            if (kk     < a4) srt[stp + kk]     = (uint8_t)NTAP;
            if (kk + 1 < a4) srt[stp + kk + 1] = (uint8_t)NTAP;
            if (kk + 2 < a4) srt[stp + kk + 2] = (uint8_t)NTAP;
        }
        // lane 15: terminal pad word at stp == total aligned size, so the
        // paired-chunk overread at A+q+4 always lands on valid tap ids
        if (lane == 15) {
            srt[stp]     = (uint8_t)NTAP;
            srt[stp + 1] = (uint8_t)NTAP;
            srt[stp + 2] = (uint8_t)NTAP;
            srt[stp + 3] = (uint8_t)NTAP;
        }

        // main accumulate: TWO chunks per iteration (8 taps), pure fp32.
        // Both srt words and all 8 w reads are address-independent.
        float run = 0.0f, cvv = 0.0f;
        int tc = 127;
        float ser[15];
        int A = 0;                               // aligned bucket start
        #pragma unroll
        for (int t = 0; t < 15; ++t) {
            int k = kt[t];
            for (int q = 0; q < k; q += 8) {
                unsigned pr1 = *(const unsigned*)(srt + A + q);      // chunk 1 (always valid)
                unsigned pr2 = *(const unsigned*)(srt + A + q + 4);  // chunk 2 or next-bucket/terminal pad
                float wa1 = w_lds[((pr1       & 0xFFu) << 6) + lane];
                float wb1 = w_lds[(((pr1 >> 8) & 0xFFu) << 6) + lane];
                float wc1 = w_lds[(((pr1 >> 16) & 0xFFu) << 6) + lane];
                float wd1 = w_lds[(( pr1 >> 24        ) << 6) + lane];
                float wa2 = w_lds[((pr2       & 0xFFu) << 6) + lane];
                float wb2 = w_lds[(((pr2 >> 8) & 0xFFu) << 6) + lane];
                float wc2 = w_lds[(((pr2 >> 16) & 0xFFu) << 6) + lane];
                float wd2 = w_lds[(( pr2 >> 24        ) << 6) + lane];
                float s1 = (wa1 + wb1) + (wc1 + wd1);
                float s2 = (wa2 + wb2) + (wc2 + wd2);
                s2 = (q + 4 < k) ? s2 : 0.0f;                        // predicate 2nd chunk
                run += (s1 + s2);
            }
            A += (k + 3) & ~3;
            ser[t] = run;
            bool cross_now = (tc == 127) && (run >= DTHRESH_F);
            if (cross_now) { tc = t; cvv = run; }            // cndmask, no branch
        }

        // cross-lane: e = min crossing time; winner = max cvv among tc==e, first-lane tie
        int e = tc;
        #pragma unroll
        for (int off = 32; off >= 1; off >>= 1) e = min(e, __shfl_xor(e, off));
        int wc = -1;
        float val = 0.0f;
        if (e < 15) {                                    // uniform branch
            float vl = (tc == e) ? cvv : 0.0f;
            float m = vl;
            #pragma unroll
            for (int off = 32; off >= 1; off >>= 1) m = fmaxf(m, __shfl_xor(m, off));
            unsigned long long mk = __ballot(vl == m);
            wc = __ffsll(mk) - 1;
            val = m;

            // winner's series -> lanes 0..14 via shfl, zero before crossing
            float ov = 0.0f;
            #pragma unroll
            for (int t = 0; t < 15; ++t) {
                float sv = __shfl(ser[t], wc);
                if (lane == t) ov = sv;
            }
            if (lane < e) ov = 0.0f;                     // monotone: below thresh before e
            if (lane < 15) series_ws[p * 16 + lane] = ov;
        }
        if (lane == 0) {
            winc_ws[p] = (int8_t)wc;
            nmap_ws[p] = (uint8_t)(wc >= 0 ? (15 - e) : 0);
            if (wc >= 0) val_ws[p] = (double)val;        // kwin consumes double
        }
    }
}

// ---------------- K3: cooperative 5-round k-winners (lexicographic key, 64 blocks) ----------------
// R3 version verbatim (known-good). Key = nm*2048 + val orders exactly as the
// reference's nm*(val + 15*max_val); 5 grid syncs total.
__global__ __launch_bounds__(256) void kwin_kernel(
        const int8_t* __restrict__ winc, const uint8_t* __restrict__ nmap,
        const double* __restrict__ val, float* __restrict__ outw,
        double* __restrict__ redv, unsigned* __restrict__ redi)
{
    cg::grid_group grid = cg::this_grid();
    const int tid  = threadIdx.x;
    const int bid  = blockIdx.x;
    const int lane = tid & 63, wvi = tid >> 6;

    __shared__ double   s_v[4];
    __shared__ unsigned s_i[4];

    int     pc[4];
    int     phh[4], pww[4];
    double  key[4];
    unsigned idx[4];
    bool    alive[4];
    #pragma unroll
    for (int k = 0; k < 4; ++k) {
        const int p = (k << 14) | (bid << 8) | tid;      // coalesced per k
        const int c = winc[p];
        alive[k] = (c >= 0);
        const double vp = alive[k] ? val[p] : 0.0;       // val only valid where winner exists
        key[k]  = (double)nmap[p] * 2048.0 + vp;         // lex (nm, val) in one double
        idx[k]  = ((unsigned)c << 16) | (unsigned)p;     // c-major flat index (tie-break)
        pc[k]   = c;
        phh[k]  = p >> 8;
        pww[k]  = p & 255;
    }

    for (int r = 0; r < 5; ++r) {
        __syncthreads();                          // protect s_v/s_i reuse across rounds
        const int par = r & 1;

        // best among my 4 positions (static indexing -> registers)
        double   bv = -1.0;
        unsigned bi = 0xFFFFFFFFu;
        #pragma unroll
        for (int k = 0; k < 4; ++k) {
            if (alive[k] && (key[k] > bv || (key[k] == bv && idx[k] < bi))) {
                bv = key[k]; bi = idx[k];
            }
        }
        // wave argmax with (key desc, fi asc) ordering
        #pragma unroll
        for (int off = 32; off >= 1; off >>= 1) {
            double   ov = __shfl_xor(bv, off);
            unsigned oi = __shfl_xor(bi, off);
            if (ov > bv || (ov == bv && oi < bi)) { bv = ov; bi = oi; }
        }
        if (lane == 0) { s_v[wvi] = bv; s_i[wvi] = bi; }
        __syncthreads();
        if (tid == 0) {
            double bbv = s_v[0]; unsigned bbi = s_i[0];
            #pragma unroll
            for (int i = 1; i < 4; ++i)
                if (s_v[i] > bbv || (s_v[i] == bbv && s_i[i] < bbi)) { bbv = s_v[i]; bbi = s_i[i]; }
            redv[par * 64 + bid] = bbv;
            redi[par * 64 + bid] = bbi;
        }
        grid.sync();

        // wave 0 of every block reduces the 64 partials -> identical winner everywhere
        if (wvi == 0) {
            double   gv = redv[par * 64 + lane];
            unsigned gi = redi[par * 64 + lane];
            #pragma unroll
            for (int off = 32; off >= 1; off >>= 1) {
                double   ov = __shfl_xor(gv, off);
                unsigned oi = __shfl_xor(gi, off);
                if (ov > gv || (ov == gv && oi < gi)) { gv = ov; gi = oi; }
            }
            if (lane == 0) { s_v[0] = gv; s_i[0] = gi; }
        }
        __syncthreads();
        const double   bbv = s_v[0];
        const unsigned bbi = s_i[0];

        const bool valid = (bbv > 0.0);          // any alive position has key >= 2048+15
        if (bid == 0 && tid == 0) {
            int wc2 = (int)(bbi >> 16), pp = (int)(bbi & 0xFFFFu);
            outw[r * 3 + 0] = valid ? (float)wc2       : -1.0f;
            outw[r * 3 + 1] = valid ? (float)(pp >> 8) : -1.0f;
            outw[r * 3 + 2] = valid ? (float)(pp & 255): -1.0f;
        }
        if (valid) {
            const int wc2 = (int)(bbi >> 16);
            const int wp  = (int)(bbi & 0xFFFFu);
            const int wh  = wp >> 8, wwv = wp & 255;
            #pragma unroll
            for (int k = 0; k < 4; ++k) {
                if (pc[k] == wc2 || (phh[k] >= wh - 3 && phh[k] <= wh + 3 &&
                                     pww[k] >= wwv - 3 && pww[k] <= wwv + 3)) alive[k] = false;
            }
        }
        // invalid round => all totals zero => later rounds invalid too (reference's
        // phantom kill of an all-zero total is inert for outputs)
    }
}

// ---------------- K4: expand winner map to full spk/pot (NON-TEMPORAL stores) ----------------
// R9 version verbatim (best measured): nt-flagged dwordx4 stores bypass L2
// write-allocate for the two 503 MB one-touch streams.
__global__ __launch_bounds__(256) void expand_kernel(
        const int8_t* __restrict__ winc, const float* __restrict__ series,
        float* __restrict__ spk, float* __restrict__ pot)
{
    int idx4 = blockIdx.x * 256 + threadIdx.x;   // < 15,728,640
    int w4 = idx4 & 63;
    int h  = (idx4 >> 6) & 255;
    int c  = (idx4 >> 14) & 63;
    int t  = idx4 >> 20;
    int pbase = h * W + (w4 << 2);
    uint32_t wcs = *reinterpret_cast<const uint32_t*>(winc + pbase);
    vfloat4 pv = (vfloat4)(0.0f);
    vfloat4 sv = (vfloat4)(0.0f);
    #pragma unroll
    for (int e2 = 0; e2 < 4; ++e2) {
        int8_t wcb = (int8_t)((wcs >> (8 * e2)) & 0xFFu);
        if ((int)wcb == c) {
            float xv = series[(size_t)(pbase + e2) * 16 + t];
            pv[e2] = xv;
            sv[e2] = (xv > 0.f) ? 1.0f : 0.0f;
        }
    }
    __builtin_nontemporal_store(sv, reinterpret_cast<vfloat4*>(spk) + idx4);
    __builtin_nontemporal_store(pv, reinterpret_cast<vfloat4*>(pot) + idx4);
}

extern "C" void kernel_launch(void* const* d_in, const int* in_sizes, int n_in,
                              void* d_out, int out_size, void* d_ws, size_t ws_size,
                              hipStream_t stream)
{
    if (ws_size < WS_NEED) return;

    const float* x  = (const float*)d_in[0];
    const float* w1 = (const float*)d_in[1];
    uint8_t* ws = (uint8_t*)d_ws;
    uint8_t* ftg    = ws + WS_FT;
    float*   series = (float*)(ws + WS_SERIES);
    int8_t*  winc   = (int8_t*)(ws + WS_WINC);
    uint8_t* nmap   = (uint8_t*)(ws + WS_NMAP);
    double*  val    = (double*)(ws + WS_VAL);
    double*  redv   = (double*)(ws + WS_RED);
    unsigned* redi  = (unsigned*)(ws + WS_RIX);

    float* spk  = (float*)d_out;
    float* pot  = spk + (size_t)T_STEPS * C_OUT * NPOS;
    float* outw = pot + (size_t)T_STEPS * C_OUT * NPOS;

    hipLaunchKernelGGL(ft_kernel,     dim3(1536),  dim3(256),  0, stream, x, ftg);
    hipLaunchKernelGGL(conv_kernel,   dim3(2048),  dim3(512),  0, stream, w1, ftg, series, winc, nmap, val);

    void* kargs[] = { (void*)&winc, (void*)&nmap, (void*)&val,
                      (void*)&outw, (void*)&redv, (void*)&redi };
    hipLaunchCooperativeKernel((const void*)kwin_kernel, dim3(64), dim3(256), kargs, 0, stream);

    hipLaunchKernelGGL(expand_kernel, dim3(61440), dim3(256),  0, stream, winc, series, spk, pot);
}

// Round 12
// 695.902 us; speedup vs baseline: 1.2381x; 1.0014x over previous
//
#include <hip/hip_runtime.h>
#include <hip/hip_cooperative_groups.h>
#include <stdint.h>

namespace cg = cooperative_groups;

static constexpr int T_STEPS = 15;
static constexpr int C_IN = 6;
static constexpr int C_OUT = 64;
static constexpr int H = 256;
static constexpr int W = 256;
static constexpr int NPOS = H * W;            // 65536
static constexpr int NTAP = 150;              // 6*5*5
#define DTHRESH_F 15.0f

typedef float vfloat4 __attribute__((ext_vector_type(4)));

// workspace layout (bytes)
static constexpr size_t WS_FT     = 0;                              // uint8 [C_IN*NPOS]
static constexpr size_t WS_SERIES = 393216;                         // float [NPOS*16]
static constexpr size_t WS_WINC   = WS_SERIES + (size_t)NPOS*16*4;  // int8  [NPOS]
static constexpr size_t WS_NMAP   = WS_WINC + (size_t)NPOS;         // uint8 [NPOS]
static constexpr size_t WS_VAL    = WS_NMAP + (size_t)NPOS;         // double[NPOS]
static constexpr size_t WS_RED    = WS_VAL + (size_t)NPOS*8;        // double[128]: round partials par0/par1 (2x64)
static constexpr size_t WS_RIX    = WS_RED + 128*8;                 // uint32[128]: round indices par0/par1
static constexpr size_t WS_NEED   = WS_RIX + 128*4;

// ---------------- K1: first-spike-time map ----------------
__global__ __launch_bounds__(256) void ft_kernel(const float* __restrict__ x,
                                                 uint8_t* __restrict__ ft) {
    int i = blockIdx.x * 256 + threadIdx.x;
    if (i >= C_IN * NPOS) return;
    int f = 15;
    #pragma unroll
    for (int t = T_STEPS - 1; t >= 0; --t) {
        if (x[(size_t)t * (C_IN * NPOS) + i] > 0.0f) f = t;
    }
    ft[i] = (uint8_t)f;
}

// ---------------- K2: per-position conv-as-sorted-accumulate + pointwise WTA ----------------
// R11 per-wave code with TWO occupancy changes only:
//  (1) ft_lds dropped - first-spike times read direct from ftg (L2-resident,
//      12 loads/lane/block, bounds-predicated; also moves those reads off the
//      binding LDS pipe onto VMEM). LDS: 38656 + 512 + 1632 = 40800 B
//      -> 4 blocks/CU (163,200 <= 163,840).
//  (2) lb(512,8): 4 blocks x 8 waves = 32 waves/CU = 8 waves/SIMD (VGPR cap 64;
//      accumulate-phase live set ~45-50 VGPRs, kt[] is SGPR via readfirstlane).
__global__ __launch_bounds__(512, 8) void conv_kernel(
        const float* __restrict__ w1, const uint8_t* __restrict__ ftg,
        float* __restrict__ series_ws, int8_t* __restrict__ winc_ws,
        uint8_t* __restrict__ nmap_ws, double* __restrict__ val_ws)
{
    __shared__ float w_lds[(NTAP + 1) * 64];                 // [tap][o]; row 150 = zeros
    __shared__ alignas(16) unsigned cnt_lds[8][16];          // per-wave
    __shared__ alignas(8) uint8_t sorted_lds[8][204];        // per-wave, 4-aligned buckets + pad

    int tid = threadIdx.x;
    int bid = blockIdx.x;                        // 0..2047
    int h  = bid >> 3;
    int w0 = (bid & 7) << 5;

    // stage weights transposed: w_lds[tap*64 + o] = w1[o*150 + tap] (coalesced reads)
    for (int i = tid; i < C_OUT * NTAP; i += 512) {
        int o = i / NTAP;
        int tap = i - o * NTAP;
        w_lds[tap * 64 + o] = w1[i];
    }
    if (tid < 64) w_lds[NTAP * 64 + tid] = 0.0f;             // zero row for pad slots
    __syncthreads();   // the ONLY block barrier

    int lane = tid & 63;
    int wvi  = tid >> 6;                         // 0..7
    unsigned* cnt = cnt_lds[wvi];
    uint8_t* srt = sorted_lds[wvi];

    for (int iter = 0; iter < 4; ++iter) {
        int xl = iter * 8 + wvi;                 // local col 0..31
        int p  = h * W + w0 + xl;

        if (lane < 16) cnt[lane] = 0;            // wave-private, no barrier

        // counting sort of the 150 taps by first-spike time (3 tap slots per lane)
        // ft read direct from global (pad-of-15 outside the image)
        int tap0 = lane, tap1 = lane + 64, tap2 = lane + 128;
        auto ftv = [&](int tap) -> unsigned {
            int c = tap / 25;
            int r = tap - c * 25;
            int kh = r / 5;
            int kw = r - kh * 5;
            int gh = h - 2 + kh;
            int gw = w0 + xl - 2 + kw;
            unsigned v = 15u;
            if (gh >= 0 && gh < H && gw >= 0 && gw < W) v = ftg[c * NPOS + gh * W + gw];
            return v;
        };
        unsigned f0 = ftv(tap0);
        unsigned f1 = ftv(tap1);
        unsigned f2 = (tap2 < NTAP) ? ftv(tap2) : 15u;
        unsigned r0 = 0, r1 = 0, r2 = 0;
        if (f0 < 15u) r0 = atomicAdd(&cnt[f0], 1u);
        if (f1 < 15u) r1 = atomicAdd(&cnt[f1], 1u);
        if (f2 < 15u) r2 = atomicAdd(&cnt[f2], 1u);

        // read all 16 counts via 4 vector loads (broadcast)
        uint4 c4[4];
        #pragma unroll
        for (int i = 0; i < 4; ++i) c4[i] = ((const uint4*)cnt)[i];
        unsigned cv_t[16];
        #pragma unroll
        for (int i = 0; i < 4; ++i) {
            cv_t[4*i+0] = c4[i].x; cv_t[4*i+1] = c4[i].y;
            cv_t[4*i+2] = c4[i].z; cv_t[4*i+3] = c4[i].w;
        }
        int kt[15];
        #pragma unroll
        for (int t = 0; t < 15; ++t) kt[t] = (int)__builtin_amdgcn_readfirstlane(cv_t[t]);

        // aligned-4 bucket starts: per-lane predicated prefix of align4(counts)
        unsigned st0 = 0, st1 = 0, st2 = 0, stp = 0;
        #pragma unroll
        for (int t = 0; t < 15; ++t) {
            unsigned a = (cv_t[t] + 3u) & ~3u;
            if ((unsigned)t < f0) st0 += a;
            if ((unsigned)t < f1) st1 += a;
            if ((unsigned)t < f2) st2 += a;
            if (t < lane) stp += a;              // pad-fill prefix for lane==t bucket; lane 15: total
        }
        if (f0 < 15u) srt[st0 + r0] = (uint8_t)tap0;
        if (f1 < 15u) srt[st1 + r1] = (uint8_t)tap1;
        if (f2 < 15u) srt[st2 + r2] = (uint8_t)tap2;

        // fill pad slots of bucket t=lane (lane<15) with tap 150 (zero weight)
        if (lane < 15) {
            unsigned kk = cnt[lane];             // final count for this bucket
            unsigned a4 = (kk + 3u) & ~3u;
            if (kk     < a4) srt[stp + kk]     = (uint8_t)NTAP;
            if (kk + 1 < a4) srt[stp + kk + 1] = (uint8_t)NTAP;
            if (kk + 2 < a4) srt[stp + kk + 2] = (uint8_t)NTAP;
        }
        // lane 15: terminal pad word at stp == total aligned size, so the
        // paired-chunk overread at A+q+4 always lands on valid tap ids
        if (lane == 15) {
            srt[stp]     = (uint8_t)NTAP;
            srt[stp + 1] = (uint8_t)NTAP;
            srt[stp + 2] = (uint8_t)NTAP;
            srt[stp + 3] = (uint8_t)NTAP;
        }

        // main accumulate: TWO chunks per iteration (8 taps), pure fp32.
        // Both srt words and all 8 w reads are address-independent.
        float run = 0.0f, cvv = 0.0f;
        int tc = 127;
        float ser[15];
        int A = 0;                               // aligned bucket start
        #pragma unroll
        for (int t = 0; t < 15; ++t) {
            int k = kt[t];
            for (int q = 0; q < k; q += 8) {
                unsigned pr1 = *(const unsigned*)(srt + A + q);      // chunk 1 (always valid)
                unsigned pr2 = *(const unsigned*)(srt + A + q + 4);  // chunk 2 or next-bucket/terminal pad
                float wa1 = w_lds[((pr1       & 0xFFu) << 6) + lane];
                float wb1 = w_lds[(((pr1 >> 8) & 0xFFu) << 6) + lane];
                float wc1 = w_lds[(((pr1 >> 16) & 0xFFu) << 6) + lane];
                float wd1 = w_lds[(( pr1 >> 24        ) << 6) + lane];
                float wa2 = w_lds[((pr2       & 0xFFu) << 6) + lane];
                float wb2 = w_lds[(((pr2 >> 8) & 0xFFu) << 6) + lane];
                float wc2 = w_lds[(((pr2 >> 16) & 0xFFu) << 6) + lane];
                float wd2 = w_lds[(( pr2 >> 24        ) << 6) + lane];
                float s1 = (wa1 + wb1) + (wc1 + wd1);
                float s2 = (wa2 + wb2) + (wc2 + wd2);
                s2 = (q + 4 < k) ? s2 : 0.0f;                        // predicate 2nd chunk
                run += (s1 + s2);
            }
            A += (k + 3) & ~3;
            ser[t] = run;
            bool cross_now = (tc == 127) && (run >= DTHRESH_F);
            if (cross_now) { tc = t; cvv = run; }            // cndmask, no branch
        }

        // cross-lane: e = min crossing time; winner = max cvv among tc==e, first-lane tie
        int e = tc;
        #pragma unroll
        for (int off = 32; off >= 1; off >>= 1) e = min(e, __shfl_xor(e, off));
        int wc = -1;
        float val = 0.0f;
        if (e < 15) {                                    // uniform branch
            float vl = (tc == e) ? cvv : 0.0f;
            float m = vl;
            #pragma unroll
            for (int off = 32; off >= 1; off >>= 1) m = fmaxf(m, __shfl_xor(m, off));
            unsigned long long mk = __ballot(vl == m);
            wc = __ffsll(mk) - 1;
            val = m;

            // winner's series -> lanes 0..14 via shfl, zero before crossing
            float ov = 0.0f;
            #pragma unroll
            for (int t = 0; t < 15; ++t) {
                float sv = __shfl(ser[t], wc);
                if (lane == t) ov = sv;
            }
            if (lane < e) ov = 0.0f;                     // monotone: below thresh before e
            if (lane < 15) series_ws[p * 16 + lane] = ov;
        }
        if (lane == 0) {
            winc_ws[p] = (int8_t)wc;
            nmap_ws[p] = (uint8_t)(wc >= 0 ? (15 - e) : 0);
            if (wc >= 0) val_ws[p] = (double)val;        // kwin consumes double
        }
    }
}

// ---------------- K3: cooperative 5-round k-winners (lexicographic key, 64 blocks) ----------------
// R3 version verbatim (known-good). Key = nm*2048 + val orders exactly as the
// reference's nm*(val + 15*max_val); 5 grid syncs total.
__global__ __launch_bounds__(256) void kwin_kernel(
        const int8_t* __restrict__ winc, const uint8_t* __restrict__ nmap,
        const double* __restrict__ val, float* __restrict__ outw,
        double* __restrict__ redv, unsigned* __restrict__ redi)
{
    cg::grid_group grid = cg::this_grid();
    const int tid  = threadIdx.x;
    const int bid  = blockIdx.x;
    const int lane = tid & 63, wvi = tid >> 6;

    __shared__ double   s_v[4];
    __shared__ unsigned s_i[4];

    int     pc[4];
    int     phh[4], pww[4];
    double  key[4];
    unsigned idx[4];
    bool    alive[4];
    #pragma unroll
    for (int k = 0; k < 4; ++k) {
        const int p = (k << 14) | (bid << 8) | tid;      // coalesced per k
        const int c = winc[p];
        alive[k] = (c >= 0);
        const double vp = alive[k] ? val[p] : 0.0;       // val only valid where winner exists
        key[k]  = (double)nmap[p] * 2048.0 + vp;         // lex (nm, val) in one double
        idx[k]  = ((unsigned)c << 16) | (unsigned)p;     // c-major flat index (tie-break)
        pc[k]   = c;
        phh[k]  = p >> 8;
        pww[k]  = p & 255;
    }

    for (int r = 0; r < 5; ++r) {
        __syncthreads();                          // protect s_v/s_i reuse across rounds
        const int par = r & 1;

        // best among my 4 positions (static indexing -> registers)
        double   bv = -1.0;
        unsigned bi = 0xFFFFFFFFu;
        #pragma unroll
        for (int k = 0; k < 4; ++k) {
            if (alive[k] && (key[k] > bv || (key[k] == bv && idx[k] < bi))) {
                bv = key[k]; bi = idx[k];
            }
        }
        // wave argmax with (key desc, fi asc) ordering
        #pragma unroll
        for (int off = 32; off >= 1; off >>= 1) {
            double   ov = __shfl_xor(bv, off);
            unsigned oi = __shfl_xor(bi, off);
            if (ov > bv || (ov == bv && oi < bi)) { bv = ov; bi = oi; }
        }
        if (lane == 0) { s_v[wvi] = bv; s_i[wvi] = bi; }
        __syncthreads();
        if (tid == 0) {
            double bbv = s_v[0]; unsigned bbi = s_i[0];
            #pragma unroll
            for (int i = 1; i < 4; ++i)
                if (s_v[i] > bbv || (s_v[i] == bbv && s_i[i] < bbi)) { bbv = s_v[i]; bbi = s_i[i]; }
            redv[par * 64 + bid] = bbv;
            redi[par * 64 + bid] = bbi;
        }
        grid.sync();

        // wave 0 of every block reduces the 64 partials -> identical winner everywhere
        if (wvi == 0) {
            double   gv = redv[par * 64 + lane];
            unsigned gi = redi[par * 64 + lane];
            #pragma unroll
            for (int off = 32; off >= 1; off >>= 1) {
                double   ov = __shfl_xor(gv, off);
                unsigned oi = __shfl_xor(gi, off);
                if (ov > gv || (ov == gv && oi < gi)) { gv = ov; gi = oi; }
            }
            if (lane == 0) { s_v[0] = gv; s_i[0] = gi; }
        }
        __syncthreads();
        const double   bbv = s_v[0];
        const unsigned bbi = s_i[0];

        const bool valid = (bbv > 0.0);          // any alive position has key >= 2048+15
        if (bid == 0 && tid == 0) {
            int wc2 = (int)(bbi >> 16), pp = (int)(bbi & 0xFFFFu);
            outw[r * 3 + 0] = valid ? (float)wc2       : -1.0f;
            outw[r * 3 + 1] = valid ? (float)(pp >> 8) : -1.0f;
            outw[r * 3 + 2] = valid ? (float)(pp & 255): -1.0f;
        }
        if (valid) {
            const int wc2 = (int)(bbi >> 16);
            const int wp  = (int)(bbi & 0xFFFFu);
            const int wh  = wp >> 8, wwv = wp & 255;
            #pragma unroll
            for (int k = 0; k < 4; ++k) {
                if (pc[k] == wc2 || (phh[k] >= wh - 3 && phh[k] <= wh + 3 &&
                                     pww[k] >= wwv - 3 && pww[k] <= wwv + 3)) alive[k] = false;
            }
        }
        // invalid round => all totals zero => later rounds invalid too (reference's
        // phantom kill of an all-zero total is inert for outputs)
    }
}

// ---------------- K4: expand winner map to full spk/pot (NON-TEMPORAL stores) ----------------
// R9 version verbatim (best measured): nt-flagged dwordx4 stores bypass L2
// write-allocate for the two 503 MB one-touch streams.
__global__ __launch_bounds__(256) void expand_kernel(
        const int8_t* __restrict__ winc, const float* __restrict__ series,
        float* __restrict__ spk, float* __restrict__ pot)
{
    int idx4 = blockIdx.x * 256 + threadIdx.x;   // < 15,728,640
    int w4 = idx4 & 63;
    int h  = (idx4 >> 6) & 255;
    int c  = (idx4 >> 14) & 63;
    int t  = idx4 >> 20;
    int pbase = h * W + (w4 << 2);
    uint32_t wcs = *reinterpret_cast<const uint32_t*>(winc + pbase);
    vfloat4 pv = (vfloat4)(0.0f);
    vfloat4 sv = (vfloat4)(0.0f);
    #pragma unroll
    for (int e2 = 0; e2 < 4; ++e2) {
        int8_t wcb = (int8_t)((wcs >> (8 * e2)) & 0xFFu);
        if ((int)wcb == c) {
            float xv = series[(size_t)(pbase + e2) * 16 + t];
            pv[e2] = xv;
            sv[e2] = (xv > 0.f) ? 1.0f : 0.0f;
        }
    }
    __builtin_nontemporal_store(sv, reinterpret_cast<vfloat4*>(spk) + idx4);
    __builtin_nontemporal_store(pv, reinterpret_cast<vfloat4*>(pot) + idx4);
}

extern "C" void kernel_launch(void* const* d_in, const int* in_sizes, int n_in,
                              void* d_out, int out_size, void* d_ws, size_t ws_size,
                              hipStream_t stream)
{
    if (ws_size < WS_NEED) return;

    const float* x  = (const float*)d_in[0];
    const float* w1 = (const float*)d_in[1];
    uint8_t* ws = (uint8_t*)d_ws;
    uint8_t* ftg    = ws + WS_FT;
    float*   series = (float*)(ws + WS_SERIES);
    int8_t*  winc   = (int8_t*)(ws + WS_WINC);
    uint8_t* nmap   = (uint8_t*)(ws + WS_NMAP);
    double*  val    = (double*)(ws + WS_VAL);
    double*  redv   = (double*)(ws + WS_RED);
    unsigned* redi  = (unsigned*)(ws + WS_RIX);

    float* spk  = (float*)d_out;
    float* pot  = spk + (size_t)T_STEPS * C_OUT * NPOS;
    float* outw = pot + (size_t)T_STEPS * C_OUT * NPOS;

    hipLaunchKernelGGL(ft_kernel,     dim3(1536),  dim3(256),  0, stream, x, ftg);
    hipLaunchKernelGGL(conv_kernel,   dim3(2048),  dim3(512),  0, stream, w1, ftg, series, winc, nmap, val);

    void* kargs[] = { (void*)&winc, (void*)&nmap, (void*)&val,
                      (void*)&outw, (void*)&redv, (void*)&redi };
    hipLaunchCooperativeKernel((const void*)kwin_kernel, dim3(64), dim3(256), kargs, 0, stream);

    hipLaunchKernelGGL(expand_kernel, dim3(61440), dim3(256),  0, stream, winc, series, spk, pot);
}